// Round 11
// baseline (212.737 us; speedup 1.0000x reference)
//
#include <hip/hip_runtime.h>

#define HD 1024
#define ID 4096
#define NR 8192

typedef float f32x4 __attribute__((ext_vector_type(4)));
typedef __bf16 bf16x8 __attribute__((ext_vector_type(8)));

__device__ inline ushort f2bf(float f) {
    union { float f; unsigned u; } v; v.f = f;
    unsigned u = v.u;
    unsigned r = (u + 0x7fffu + ((u >> 16) & 1u)) >> 16;  // RNE
    return (ushort)r;
}

__device__ inline float wave_sum(float v) {
#pragma unroll
    for (int o = 32; o > 0; o >>= 1) v += __shfl_xor(v, o, 64);
    return v;
}

template <int N> __device__ __forceinline__ void vmw() {
    static_assert(N >= 0 && N <= 4, "vmcnt");
    if constexpr (N == 0) asm volatile("s_waitcnt vmcnt(0)" ::: "memory");
    else if constexpr (N == 1) asm volatile("s_waitcnt vmcnt(1)" ::: "memory");
    else if constexpr (N == 2) asm volatile("s_waitcnt vmcnt(2)" ::: "memory");
    else if constexpr (N == 3) asm volatile("s_waitcnt vmcnt(3)" ::: "memory");
    else asm volatile("s_waitcnt vmcnt(4)" ::: "memory");
}
__device__ __forceinline__ void barrier_() {
    __builtin_amdgcn_sched_barrier(0);
    __builtin_amdgcn_s_barrier();
    __builtin_amdgcn_sched_barrier(0);
}
__device__ __forceinline__ void lgk0_() {
    asm volatile("s_waitcnt lgkmcnt(0)" ::: "memory");
    __builtin_amdgcn_sched_barrier(0);
}

// YOSO activation: t = 1 - acos(s)/pi via A&S 4.4.45 (|err| <= 6.7e-5 rad), out t^9.
__device__ __forceinline__ float yoso_act(float v) {
    float s = fminf(fmaxf(v, -0.999999f), 0.999999f);
    float a = fabsf(s);
    float p = 0.49998557f + a * (-0.06751706f + a * (0.02363794f - a * 0.00596170f));
    float q = sqrtf(1.0f - a) * p;           // acos(|s|)/pi
    float tt = (s >= 0.0f) ? 1.0f - q : q;
    float t2 = tt * tt, t4 = t2 * t2, t8 = t4 * t4;
    return t8 * tt;
}

// ======== GEMM1: 128x128, BK=32, DOUBLE-BUFFERED, 4 waves, 32 KiB LDS, 4 blk/CU ========
// stage(t+1) issued BEFORE compute(t): vmcnt(0) at step end waits on ~400-cyc-old loads
// -> L2 latency hidden by ILP; ONE barrier/step (write-buf != read-buf, no WAR barrier).
// LDS layout per tile (8 KiB): [128 rows][64 B], slot permutation  slot ^ ((row>>1)&3)
// (2-way bank aliasing only = free). Source pre-swizzled, reads XOR (rule 21).
// Grid MUST be 2048 = 8 xcd * 32 cu * 8 rnd (banded map, per-XCD A 2 MiB + B 1 MiB).
__global__ __launch_bounds__(256, 4) void gemm1v_kernel(
    const ushort* __restrict__ Ap, const ushort* __restrict__ Bp,
    ushort* __restrict__ Cp, int N, int K, int nt) {
    __shared__ char lds[32768] __attribute__((aligned(16)));
    const int tid = threadIdx.x;
    const int w = tid >> 6, lane = tid & 63;
    const int bid = blockIdx.x;
    const int xcd = bid & 7, cu = (bid >> 3) & 31, rnd = bid >> 8;
    const int brow = (xcd * 8 + (cu >> 2)) * 128;   // per-XCD A footprint 2 MiB
    const int bcol = (rnd * 4 + (cu & 3)) * 128;    // per-XCD B footprint 1 MiB
    const int wr = (w >> 1) * 64;
    const int wc = (w & 1) * 64;
    f32x4 acc[4][4] = {};

    // stage one 32-col K-slice of A and B into buffer db (4 loads/thread total).
    // load unit (w,i) covers LDS bytes [(w*2+i)*1024, +1024); lane writes +lane*16.
    // byte b -> row = b>>6, slot = (b>>4)&3; global col-slice = slot ^ ((row>>1)&3).
    auto stage = [&](int t, int db) {
#pragma unroll
        for (int i = 0; i < 2; ++i) {
            int r = (w * 2 + i) * 16 + (lane >> 2);
            int cs = (lane & 3) ^ ((r >> 1) & 3);
            const char* src = (const char*)(Ap + (size_t)(brow + r) * K + t * 32 + cs * 8);
            __builtin_amdgcn_global_load_lds(
                (const __attribute__((address_space(1))) void*)src,
                (__attribute__((address_space(3))) void*)&lds[db * 16384 + (w * 2 + i) * 1024],
                16, 0, 0);
        }
#pragma unroll
        for (int i = 0; i < 2; ++i) {
            int r = (w * 2 + i) * 16 + (lane >> 2);
            int cs = (lane & 3) ^ ((r >> 1) & 3);
            const char* src = (const char*)(Bp + (size_t)(bcol + r) * K + t * 32 + cs * 8);
            __builtin_amdgcn_global_load_lds(
                (const __attribute__((address_space(1))) void*)src,
                (__attribute__((address_space(3))) void*)&lds[db * 16384 + 8192 + (w * 2 + i) * 1024],
                16, 0, 0);
        }
    };

    stage(0, 0);
    vmw<0>();
    barrier_();

    for (int t = 0; t < nt; ++t) {
        const int db = t & 1;
        const bool more = (t + 1 < nt);
        if (more) stage(t + 1, db ^ 1);   // issue FIRST: latency hides under compute(t)
        const char* Ab = lds + db * 16384;
        const char* Bb = lds + db * 16384 + 8192;
        bf16x8 af[4], bfr[4];
        const int s = lane >> 4;
#pragma unroll
        for (int m = 0; m < 4; ++m) {
            int row = wr + m * 16 + (lane & 15);
            af[m] = *(const bf16x8*)(Ab + row * 64 + (((s ^ (row >> 1)) & 3) << 4));
        }
#pragma unroll
        for (int n = 0; n < 4; ++n) {
            int row = wc + n * 16 + (lane & 15);
            bfr[n] = *(const bf16x8*)(Bb + row * 64 + (((s ^ (row >> 1)) & 3) << 4));
        }
        lgk0_();
        __builtin_amdgcn_s_setprio(1);
#pragma unroll
        for (int m = 0; m < 4; ++m)
#pragma unroll
            for (int n = 0; n < 4; ++n)
                acc[m][n] = __builtin_amdgcn_mfma_f32_16x16x32_bf16(
                    af[m], bfr[n], acc[m][n], 0, 0, 0);
        __builtin_amdgcn_s_setprio(0);
        __builtin_amdgcn_sched_barrier(0);
        if (more) {
            vmw<0>();       // stage(t+1) landed (issued ~400 cyc ago)
            barrier_();
        }
    }

    // epilogue: in-register act, direct ushort stores (16-lane groups = 32-B segments)
    const int crow0 = brow + wr + ((lane >> 4) << 2);
    const int ccol0 = bcol + wc + (lane & 15);
#pragma unroll
    for (int m = 0; m < 4; ++m)
#pragma unroll
        for (int n = 0; n < 4; ++n)
#pragma unroll
            for (int r = 0; r < 4; ++r) {
                int row = crow0 + m * 16 + r;
                int col = ccol0 + n * 16;
                Cp[(size_t)row * N + col] = f2bf(yoso_act(acc[m][n][r]));
            }
}

// ================= GEMM2: proven 8-phase 256x128 (ACT=0, f32 out) ==========
template <int NW, int ACT>
__global__ __launch_bounds__(512, 2) void gemm8p_kernel(
    const ushort* __restrict__ Ap, const ushort* __restrict__ Bp,
    void* __restrict__ Cv, int N, int K, int nt) {
    __shared__ char lds[131072] __attribute__((aligned(16)));
    const int tid = threadIdx.x;
    const int w = tid >> 6, l = tid & 63;
    const int wm = w >> 2, wn = w & 3;
    const int bid = blockIdx.x;
    const int swz = (bid & 7) * ((int)gridDim.x >> 3) + (bid >> 3);
    const int brow = (swz & 31) * 256;
    const int bcol = (swz >> 5) * (128 * NW);
    const int colsw = ((l & 7) ^ (l >> 3)) << 4;

    f32x4 acc[8][2 * NW] = {};
    bf16x8 areg[4][2];
    bf16x8 breg[2][NW][2];

    auto sA = [&](int t, int mh) {
#pragma unroll
        for (int i = 0; i < 2; ++i) {
            int s = (w * 2 + i) * 8 + (l >> 3);
            int r = ((s >> 6) << 7) + mh * 64 + (s & 63);
            const char* src = (const char*)Ap + (((size_t)(brow + r) * K + t * 64) << 1) + colsw;
            __builtin_amdgcn_global_load_lds(
                (const __attribute__((address_space(1))) void*)src,
                (__attribute__((address_space(3))) void*)&lds[(t & 1) * 32768 + mh * 16384 +
                                                              (w * 2 + i) * 1024],
                16, 0, 0);
        }
    };
    auto sB = [&](int t, int nh) {
#pragma unroll
        for (int i = 0; i < NW; ++i) {
            constexpr int SH = (NW == 2) ? 5 : 4;
            int s = (w * NW + i) * 8 + (l >> 3);
            int r = ((s >> SH) << (SH + 1)) + nh * (16 * NW) + (s & (16 * NW - 1));
            const char* src = (const char*)Bp + (((size_t)(bcol + r) * K + t * 64) << 1) + colsw;
            __builtin_amdgcn_global_load_lds(
                (const __attribute__((address_space(1))) void*)src,
                (__attribute__((address_space(3))) void*)&lds[65536 + (t & 1) * (NW * 16384) +
                                                              nh * (NW * 8192) + (w * NW + i) * 1024],
                16, 0, 0);
        }
    };
    auto load_a = [&](int db, int mh) {
#pragma unroll
        for (int m = 0; m < 4; ++m)
#pragma unroll
            for (int ks = 0; ks < 2; ++ks) {
                int s = wm * 64 + m * 16 + (l & 15);
                areg[m][ks] = *(const bf16x8*)(lds + db * 32768 + mh * 16384 + s * 128 +
                                               ((ks * 64 + ((l >> 4) << 4)) ^ ((l & 7) << 4)));
            }
    };
    auto load_b = [&](int db, int nh) {
#pragma unroll
        for (int n = 0; n < NW; ++n)
#pragma unroll
            for (int ks = 0; ks < 2; ++ks) {
                int s = wn * (16 * NW) + n * 16 + (l & 15);
                breg[nh][n][ks] = *(const bf16x8*)(lds + 65536 + db * (NW * 16384) +
                                                   nh * (NW * 8192) + s * 128 +
                                                   ((ks * 64 + ((l >> 4) << 4)) ^ ((l & 7) << 4)));
            }
    };
    auto mma = [&](int mh, int nh) {
#pragma unroll
        for (int m = 0; m < 4; ++m)
#pragma unroll
            for (int n = 0; n < NW; ++n)
#pragma unroll
                for (int ks = 0; ks < 2; ++ks)
                    acc[mh * 4 + m][nh * NW + n] = __builtin_amdgcn_mfma_f32_16x16x32_bf16(
                        areg[m][ks], breg[nh][n][ks], acc[mh * 4 + m][nh * NW + n], 0, 0, 0);
    };

    sA(0, 0); sB(0, 0); sB(0, 1); sA(0, 1);
    vmw<3>();
    barrier_();

    for (int t = 0; t < nt; ++t) {
        const int db = t & 1;
        const bool more = (t + 1 < nt);
        load_a(db, 0); load_b(db, 0);
        if (more) sA(t + 1, 0);
        barrier_(); lgk0_();
        __builtin_amdgcn_s_setprio(1); mma(0, 0); __builtin_amdgcn_s_setprio(0);
        __builtin_amdgcn_sched_barrier(0);
        if (more) vmw<4>(); else vmw<2>();
        barrier_();
        load_b(db, 1);
        if (more) sB(t + 1, 0);
        barrier_(); lgk0_();
        __builtin_amdgcn_s_setprio(1); mma(0, 1); __builtin_amdgcn_s_setprio(0);
        __builtin_amdgcn_sched_barrier(0);
        if (more) vmw<3>(); else vmw<0>();
        barrier_();
        load_a(db, 1);
        if (more) sB(t + 1, 1);
        barrier_(); lgk0_();
        __builtin_amdgcn_s_setprio(1); mma(1, 1); __builtin_amdgcn_s_setprio(0);
        barrier_();
        if (more) sA(t + 1, 1);
        barrier_();
        __builtin_amdgcn_s_setprio(1); mma(1, 0); __builtin_amdgcn_s_setprio(0);
        __builtin_amdgcn_sched_barrier(0);
        if (more) vmw<3>();
        barrier_();
    }

    char* wsl = lds + w * 16384;
    constexpr int E = ACT ? 2 : 4;
    constexpr int BPR = NW * 32 * E;
    constexpr int LPR = BPR / 16;
    constexpr int RPI = 64 / LPR;
#pragma unroll
    for (int m = 0; m < 8; ++m)
#pragma unroll
        for (int n = 0; n < 2 * NW; ++n)
#pragma unroll
            for (int r = 0; r < 4; ++r) {
                int row = m * 16 + ((l >> 4) << 2) + r;
                int colb = (n * 16 + (l & 15)) * E;
                float v = acc[m][n][r];
                if (ACT) {
                    *(ushort*)(wsl + row * 128 + (colb ^ ((row & 7) << 4))) = f2bf(yoso_act(v));
                } else {
                    *(float*)(wsl + row * 128 + (colb ^ ((row & 7) << 4))) = v;
                }
            }
    asm volatile("s_waitcnt lgkmcnt(0)" ::: "memory");
#pragma unroll
    for (int it = 0; it < 2 * LPR; ++it) {
        int row = it * RPI + l / LPR;
        int cb = (l % LPR) * 16;
        uint4 d = *(const uint4*)(wsl + row * 128 + (cb ^ ((row & 7) << 4)));
        int grow = brow + wm * 128 + row;
        size_t off = ((size_t)grow * N + (bcol + wn * (NW * 32))) * E + cb;
        *(uint4*)((char*)Cv + off) = d;
    }
}

// ---------------- Kernel 1: LayerNorm + l2-normalize -> Q bf16 ----------------
__global__ __launch_bounds__(256) void ln_qnorm_kernel(
    const float* __restrict__ x, const float* __restrict__ w,
    const float* __restrict__ b, ushort* __restrict__ Q) {
    __shared__ float red[2][4];
    __shared__ float red2[4];
    const int row = blockIdx.x, t = threadIdx.x;
    const int lane = t & 63, wid = t >> 6;
    const float4 v = reinterpret_cast<const float4*>(x + (size_t)row * HD)[t];
    float s  = v.x + v.y + v.z + v.w;
    float ss = v.x*v.x + v.y*v.y + v.z*v.z + v.w*v.w;
    s = wave_sum(s); ss = wave_sum(ss);
    if (lane == 0) { red[0][wid] = s; red[1][wid] = ss; }
    __syncthreads();
    float st  = red[0][0] + red[0][1] + red[0][2] + red[0][3];
    float sst = red[1][0] + red[1][1] + red[1][2] + red[1][3];
    float mu   = st * (1.0f / HD);
    float var  = sst * (1.0f / HD) - mu * mu;
    float rstd = rsqrtf(var + 1e-12f);
    const float4 wv = reinterpret_cast<const float4*>(w)[t];
    const float4 bv = reinterpret_cast<const float4*>(b)[t];
    float y0 = (v.x - mu) * rstd * wv.x + bv.x;
    float y1 = (v.y - mu) * rstd * wv.y + bv.y;
    float y2 = (v.z - mu) * rstd * wv.z + bv.z;
    float y3 = (v.w - mu) * rstd * wv.w + bv.w;
    float n2 = wave_sum(y0*y0 + y1*y1 + y2*y2 + y3*y3);
    if (lane == 0) red2[wid] = n2;
    __syncthreads();
    float nt = red2[0] + red2[1] + red2[2] + red2[3];
    float sc = 1.0f / fmaxf(sqrtf(nt), 1e-12f);
    ushort4 o;
    o.x = f2bf(y0 * sc); o.y = f2bf(y1 * sc);
    o.z = f2bf(y2 * sc); o.w = f2bf(y3 * sc);
    reinterpret_cast<ushort4*>(Q + (size_t)row * HD)[t] = o;
}

// ---------------- Kernel 2: l2-normalize k_weight rows -> Kn bf16 ----------------
__global__ __launch_bounds__(256) void knorm_kernel(
    const float* __restrict__ kw, ushort* __restrict__ Kn) {
    __shared__ float red2[4];
    const int row = blockIdx.x, t = threadIdx.x;
    const int lane = t & 63, wid = t >> 6;
    const float4 v = reinterpret_cast<const float4*>(kw + (size_t)row * HD)[t];
    float n2 = wave_sum(v.x*v.x + v.y*v.y + v.z*v.z + v.w*v.w);
    if (lane == 0) red2[wid] = n2;
    __syncthreads();
    float nt = red2[0] + red2[1] + red2[2] + red2[3];
    float sc = 1.0f / fmaxf(sqrtf(nt), 1e-12f);
    ushort4 o;
    o.x = f2bf(v.x * sc); o.y = f2bf(v.y * sc);
    o.z = f2bf(v.z * sc); o.w = f2bf(v.w * sc);
    reinterpret_cast<ushort4*>(Kn + (size_t)row * HD)[t] = o;
}

// ---------------- Kernel 3: transpose+cast q_weight [I][H] -> VT bf16 [H][I] ----------------
__global__ __launch_bounds__(256) void tcvt_kernel(
    const float* __restrict__ V, ushort* __restrict__ VT) {
    __shared__ float tile[64][65];
    const int t = threadIdx.x;
    const int bi = blockIdx.x * 64, bh = blockIdx.y * 64;
    const int r0 = t >> 4, c0 = (t & 15) << 2;
#pragma unroll
    for (int rr = 0; rr < 64; rr += 16) {
        float4 val = *reinterpret_cast<const float4*>(
            &V[(size_t)(bi + rr + r0) * HD + bh + c0]);
        tile[rr + r0][c0 + 0] = val.x; tile[rr + r0][c0 + 1] = val.y;
        tile[rr + r0][c0 + 2] = val.z; tile[rr + r0][c0 + 3] = val.w;
    }
    __syncthreads();
#pragma unroll
    for (int rr = 0; rr < 64; rr += 16) {
        ushort4 o;
        o.x = f2bf(tile[c0 + 0][rr + r0]);
        o.y = f2bf(tile[c0 + 1][rr + r0]);
        o.z = f2bf(tile[c0 + 2][rr + r0]);
        o.w = f2bf(tile[c0 + 3][rr + r0]);
        *reinterpret_cast<ushort4*>(&VT[(size_t)(bh + rr + r0) * ID + bi + c0]) = o;
    }
}

// ---------------- Kernel 6: in-place row l2-normalize + bias ----------------
__global__ __launch_bounds__(256) void outnorm_kernel(
    float* __restrict__ X, const float* __restrict__ bias) {
    __shared__ float red2[4];
    const int row = blockIdx.x, t = threadIdx.x;
    const int lane = t & 63, wid = t >> 6;
    float4 v = reinterpret_cast<float4*>(X + (size_t)row * HD)[t];
    float n2 = wave_sum(v.x*v.x + v.y*v.y + v.z*v.z + v.w*v.w);
    if (lane == 0) red2[wid] = n2;
    __syncthreads();
    float nt = red2[0] + red2[1] + red2[2] + red2[3];
    float sc = 1.0f / fmaxf(sqrtf(nt), 1e-12f);
    const float4 bv = reinterpret_cast<const float4*>(bias)[t];
    float4 o;
    o.x = v.x * sc + bv.x; o.y = v.y * sc + bv.y;
    o.z = v.z * sc + bv.z; o.w = v.w * sc + bv.w;
    reinterpret_cast<float4*>(X + (size_t)row * HD)[t] = o;
}

extern "C" void kernel_launch(void* const* d_in, const int* in_sizes, int n_in,
                              void* d_out, int out_size, void* d_ws, size_t ws_size,
                              hipStream_t stream) {
    const float* hs   = (const float*)d_in[0];  // hidden_states [4,2048,1024]
    const float* lnw  = (const float*)d_in[1];  // ln_weight [1024]
    const float* lnb  = (const float*)d_in[2];  // ln_bias [1024]
    const float* kw   = (const float*)d_in[3];  // k_weight [4096,1024]
    const float* qw   = (const float*)d_in[4];  // q_weight [4096,1024]
    const float* bias = (const float*)d_in[5];  // bias [1024]
    float* out = (float*)d_out;

    char* ws = (char*)d_ws;
    ushort* Q    = (ushort*)(ws);                                  // 16 MiB
    ushort* Kn   = (ushort*)(ws + (size_t)16777216);               //  8 MiB
    ushort* VT   = (ushort*)(ws + (size_t)16777216 + 8388608);     //  8 MiB
    ushort* Bmat = (ushort*)(ws + (size_t)16777216 + 2 * 8388608); // 64 MiB

    ln_qnorm_kernel<<<NR, 256, 0, stream>>>(hs, lnw, lnb, Q);
    knorm_kernel<<<ID, 256, 0, stream>>>(kw, Kn);
    tcvt_kernel<<<dim3(ID / 64, HD / 64), 256, 0, stream>>>(qw, VT);
    // GEMM1: [8192,1024] x [4096,1024]^T -> act -> Bmat bf16 [8192,4096]
    //        128x128 BK=32 double-buffered, 4 blk/CU; grid 2048 = 8*32*8
    gemm1v_kernel<<<(NR / 128) * (ID / 128), 256, 0, stream>>>(
        Q, Kn, Bmat, ID, HD, HD / 32);
    // GEMM2: [8192,4096] x [1024,4096]^T -> out f32 [8192,1024]
    gemm8p_kernel<1, 0><<<(NR / 256) * (HD / 128), 512, 0, stream>>>(
        Bmat, VT, (void*)out, HD, ID, ID / 64);
    outnorm_kernel<<<NR, 256, 0, stream>>>(out, bias);
}

// Round 12
// 205.987 us; speedup vs baseline: 1.0328x; 1.0328x over previous
//
#include <hip/hip_runtime.h>

#define HD 1024
#define ID 4096
#define NR 8192

typedef float f32x4 __attribute__((ext_vector_type(4)));
typedef __bf16 bf16x8 __attribute__((ext_vector_type(8)));

__device__ inline ushort f2bf(float f) {
    union { float f; unsigned u; } v; v.f = f;
    unsigned u = v.u;
    unsigned r = (u + 0x7fffu + ((u >> 16) & 1u)) >> 16;  // RNE
    return (ushort)r;
}

__device__ inline float wave_sum(float v) {
#pragma unroll
    for (int o = 32; o > 0; o >>= 1) v += __shfl_xor(v, o, 64);
    return v;
}

template <int N> __device__ __forceinline__ void vmw() {
    static_assert(N >= 0 && N <= 4, "vmcnt");
    if constexpr (N == 0) asm volatile("s_waitcnt vmcnt(0)" ::: "memory");
    else if constexpr (N == 1) asm volatile("s_waitcnt vmcnt(1)" ::: "memory");
    else if constexpr (N == 2) asm volatile("s_waitcnt vmcnt(2)" ::: "memory");
    else if constexpr (N == 3) asm volatile("s_waitcnt vmcnt(3)" ::: "memory");
    else asm volatile("s_waitcnt vmcnt(4)" ::: "memory");
}
__device__ __forceinline__ void barrier_() {
    __builtin_amdgcn_sched_barrier(0);
    __builtin_amdgcn_s_barrier();
    __builtin_amdgcn_sched_barrier(0);
}
__device__ __forceinline__ void lgk0_() {
    asm volatile("s_waitcnt lgkmcnt(0)" ::: "memory");
    __builtin_amdgcn_sched_barrier(0);
}

// YOSO activation: t = 1 - acos(s)/pi via A&S 4.4.45 (|err| <= 6.7e-5 rad), out t^9.
__device__ __forceinline__ float yoso_act(float v) {
    float s = fminf(fmaxf(v, -0.999999f), 0.999999f);
    float a = fabsf(s);
    float p = 0.49998557f + a * (-0.06751706f + a * (0.02363794f - a * 0.00596170f));
    float q = sqrtf(1.0f - a) * p;           // acos(|s|)/pi
    float tt = (s >= 0.0f) ? 1.0f - q : q;
    float t2 = tt * tt, t4 = t2 * t2, t8 = t4 * t4;
    return t8 * tt;
}

// ======== GEMM1: 128x128, BK=64, DOUBLE-BUFFERED (64 KiB), 4 waves, 2 blk/CU ========
// One barrier + one vmcnt per K-step; stage(t+1) issued BEFORE compute(t) so the
// vmcnt(0) waits on ~700-cyc-old loads (8 ds_read_b128 + 32 MFMA in between).
// Same proven swizzle as R10 (source pre-swizzle + read XOR; conflicts = 0).
// Grid MUST be 2048 = 8 xcd * 32 cu * 8 rnd (banded map).
__global__ __launch_bounds__(256, 2) void gemm1w_kernel(
    const ushort* __restrict__ Ap, const ushort* __restrict__ Bp,
    ushort* __restrict__ Cp, int N, int K, int nt) {
    __shared__ char lds[65536] __attribute__((aligned(16)));
    const int tid = threadIdx.x;
    const int w = tid >> 6, lane = tid & 63;
    const int bid = blockIdx.x;
    const int xcd = bid & 7, cu = (bid >> 3) & 31, rnd = bid >> 8;
    const int brow = (xcd * 8 + (cu >> 2)) * 128;   // per-XCD A footprint 2 MiB
    const int bcol = (rnd * 4 + (cu & 3)) * 128;    // per-XCD B footprint 1 MiB
    const int wr = (w >> 1) * 64;
    const int wc = (w & 1) * 64;
    f32x4 acc[4][4] = {};
    const int srow = lane >> 3;
    const int scolb = ((lane & 7) ^ (lane >> 3)) << 4;  // pre-swizzled source col (bytes)

    // stage one BK=64 K-slice (A 16K + B 16K) into buffer db: 8 loads/thread
    auto stage = [&](int t, int db) {
#pragma unroll
        for (int it = 0; it < 4; ++it) {
            const int rb = w * 32 + it * 8;
            const char* ga = (const char*)(Ap + (size_t)(brow + rb + srow) * K + t * 64) + scolb;
            const char* gb = (const char*)(Bp + (size_t)(bcol + rb + srow) * K + t * 64) + scolb;
            __builtin_amdgcn_global_load_lds(
                (const __attribute__((address_space(1))) void*)ga,
                (__attribute__((address_space(3))) void*)&lds[db * 32768 + rb * 128], 16, 0, 0);
            __builtin_amdgcn_global_load_lds(
                (const __attribute__((address_space(1))) void*)gb,
                (__attribute__((address_space(3))) void*)&lds[db * 32768 + 16384 + rb * 128],
                16, 0, 0);
        }
    };

    stage(0, 0);
    vmw<0>();
    barrier_();

    for (int t = 0; t < nt; ++t) {
        const int db = t & 1;
        const bool more = (t + 1 < nt);
        if (more) stage(t + 1, db ^ 1);   // issue FIRST: latency hides under compute(t)
        const char* Ab = lds + db * 32768;
        const char* Bb = lds + db * 32768 + 16384;
#pragma unroll
        for (int ks = 0; ks < 2; ++ks) {
            bf16x8 af[4], bfr[4];
            const int colb = ks * 64 + ((lane >> 4) << 4);
            const int xk = (lane & 7) << 4;
#pragma unroll
            for (int m = 0; m < 4; ++m)
                af[m] = *(const bf16x8*)(Ab + (wr + m * 16 + (lane & 15)) * 128 + (colb ^ xk));
#pragma unroll
            for (int n = 0; n < 4; ++n)
                bfr[n] = *(const bf16x8*)(Bb + (wc + n * 16 + (lane & 15)) * 128 + (colb ^ xk));
#pragma unroll
            for (int m = 0; m < 4; ++m)
#pragma unroll
                for (int n = 0; n < 4; ++n)
                    acc[m][n] = __builtin_amdgcn_mfma_f32_16x16x32_bf16(
                        af[m], bfr[n], acc[m][n], 0, 0, 0);
        }
        if (more) {
            __builtin_amdgcn_sched_barrier(0);
            vmw<0>();       // stage(t+1) landed (issued ~700 cyc ago)
            barrier_();     // all waves done reading buf db -> next step may overwrite it
        }
    }

    // epilogue: in-register act, direct ushort stores (16-lane groups = 32-B segments)
    const int crow0 = brow + wr + ((lane >> 4) << 2);
    const int ccol0 = bcol + wc + (lane & 15);
#pragma unroll
    for (int m = 0; m < 4; ++m)
#pragma unroll
        for (int n = 0; n < 4; ++n)
#pragma unroll
            for (int r = 0; r < 4; ++r) {
                int row = crow0 + m * 16 + r;
                int col = ccol0 + n * 16;
                Cp[(size_t)row * N + col] = f2bf(yoso_act(acc[m][n][r]));
            }
}

// ================= GEMM2: proven 8-phase 256x128 (ACT=0, f32 out) ==========
template <int NW, int ACT>
__global__ __launch_bounds__(512, 2) void gemm8p_kernel(
    const ushort* __restrict__ Ap, const ushort* __restrict__ Bp,
    void* __restrict__ Cv, int N, int K, int nt) {
    __shared__ char lds[131072] __attribute__((aligned(16)));
    const int tid = threadIdx.x;
    const int w = tid >> 6, l = tid & 63;
    const int wm = w >> 2, wn = w & 3;
    const int bid = blockIdx.x;
    const int swz = (bid & 7) * ((int)gridDim.x >> 3) + (bid >> 3);
    const int brow = (swz & 31) * 256;
    const int bcol = (swz >> 5) * (128 * NW);
    const int colsw = ((l & 7) ^ (l >> 3)) << 4;

    f32x4 acc[8][2 * NW] = {};
    bf16x8 areg[4][2];
    bf16x8 breg[2][NW][2];

    auto sA = [&](int t, int mh) {
#pragma unroll
        for (int i = 0; i < 2; ++i) {
            int s = (w * 2 + i) * 8 + (l >> 3);
            int r = ((s >> 6) << 7) + mh * 64 + (s & 63);
            const char* src = (const char*)Ap + (((size_t)(brow + r) * K + t * 64) << 1) + colsw;
            __builtin_amdgcn_global_load_lds(
                (const __attribute__((address_space(1))) void*)src,
                (__attribute__((address_space(3))) void*)&lds[(t & 1) * 32768 + mh * 16384 +
                                                              (w * 2 + i) * 1024],
                16, 0, 0);
        }
    };
    auto sB = [&](int t, int nh) {
#pragma unroll
        for (int i = 0; i < NW; ++i) {
            constexpr int SH = (NW == 2) ? 5 : 4;
            int s = (w * NW + i) * 8 + (l >> 3);
            int r = ((s >> SH) << (SH + 1)) + nh * (16 * NW) + (s & (16 * NW - 1));
            const char* src = (const char*)Bp + (((size_t)(bcol + r) * K + t * 64) << 1) + colsw;
            __builtin_amdgcn_global_load_lds(
                (const __attribute__((address_space(1))) void*)src,
                (__attribute__((address_space(3))) void*)&lds[65536 + (t & 1) * (NW * 16384) +
                                                              nh * (NW * 8192) + (w * NW + i) * 1024],
                16, 0, 0);
        }
    };
    auto load_a = [&](int db, int mh) {
#pragma unroll
        for (int m = 0; m < 4; ++m)
#pragma unroll
            for (int ks = 0; ks < 2; ++ks) {
                int s = wm * 64 + m * 16 + (l & 15);
                areg[m][ks] = *(const bf16x8*)(lds + db * 32768 + mh * 16384 + s * 128 +
                                               ((ks * 64 + ((l >> 4) << 4)) ^ ((l & 7) << 4)));
            }
    };
    auto load_b = [&](int db, int nh) {
#pragma unroll
        for (int n = 0; n < NW; ++n)
#pragma unroll
            for (int ks = 0; ks < 2; ++ks) {
                int s = wn * (16 * NW) + n * 16 + (l & 15);
                breg[nh][n][ks] = *(const bf16x8*)(lds + 65536 + db * (NW * 16384) +
                                                   nh * (NW * 8192) + s * 128 +
                                                   ((ks * 64 + ((l >> 4) << 4)) ^ ((l & 7) << 4)));
            }
    };
    auto mma = [&](int mh, int nh) {
#pragma unroll
        for (int m = 0; m < 4; ++m)
#pragma unroll
            for (int n = 0; n < NW; ++n)
#pragma unroll
                for (int ks = 0; ks < 2; ++ks)
                    acc[mh * 4 + m][nh * NW + n] = __builtin_amdgcn_mfma_f32_16x16x32_bf16(
                        areg[m][ks], breg[nh][n][ks], acc[mh * 4 + m][nh * NW + n], 0, 0, 0);
    };

    sA(0, 0); sB(0, 0); sB(0, 1); sA(0, 1);
    vmw<3>();
    barrier_();

    for (int t = 0; t < nt; ++t) {
        const int db = t & 1;
        const bool more = (t + 1 < nt);
        load_a(db, 0); load_b(db, 0);
        if (more) sA(t + 1, 0);
        barrier_(); lgk0_();
        __builtin_amdgcn_s_setprio(1); mma(0, 0); __builtin_amdgcn_s_setprio(0);
        __builtin_amdgcn_sched_barrier(0);
        if (more) vmw<4>(); else vmw<2>();
        barrier_();
        load_b(db, 1);
        if (more) sB(t + 1, 0);
        barrier_(); lgk0_();
        __builtin_amdgcn_s_setprio(1); mma(0, 1); __builtin_amdgcn_s_setprio(0);
        __builtin_amdgcn_sched_barrier(0);
        if (more) vmw<3>(); else vmw<0>();
        barrier_();
        load_a(db, 1);
        if (more) sB(t + 1, 1);
        barrier_(); lgk0_();
        __builtin_amdgcn_s_setprio(1); mma(1, 1); __builtin_amdgcn_s_setprio(0);
        barrier_();
        if (more) sA(t + 1, 1);
        barrier_();
        __builtin_amdgcn_s_setprio(1); mma(1, 0); __builtin_amdgcn_s_setprio(0);
        __builtin_amdgcn_sched_barrier(0);
        if (more) vmw<3>();
        barrier_();
    }

    char* wsl = lds + w * 16384;
    constexpr int E = ACT ? 2 : 4;
    constexpr int BPR = NW * 32 * E;
    constexpr int LPR = BPR / 16;
    constexpr int RPI = 64 / LPR;
#pragma unroll
    for (int m = 0; m < 8; ++m)
#pragma unroll
        for (int n = 0; n < 2 * NW; ++n)
#pragma unroll
            for (int r = 0; r < 4; ++r) {
                int row = m * 16 + ((l >> 4) << 2) + r;
                int colb = (n * 16 + (l & 15)) * E;
                float v = acc[m][n][r];
                if (ACT) {
                    *(ushort*)(wsl + row * 128 + (colb ^ ((row & 7) << 4))) = f2bf(yoso_act(v));
                } else {
                    *(float*)(wsl + row * 128 + (colb ^ ((row & 7) << 4))) = v;
                }
            }
    asm volatile("s_waitcnt lgkmcnt(0)" ::: "memory");
#pragma unroll
    for (int it = 0; it < 2 * LPR; ++it) {
        int row = it * RPI + l / LPR;
        int cb = (l % LPR) * 16;
        uint4 d = *(const uint4*)(wsl + row * 128 + (cb ^ ((row & 7) << 4)));
        int grow = brow + wm * 128 + row;
        size_t off = ((size_t)grow * N + (bcol + wn * (NW * 32))) * E + cb;
        *(uint4*)((char*)Cv + off) = d;
    }
}

// ---------------- Merged prep: LN+qnorm rows | knorm rows | q_weight transpose ----------------
__global__ __launch_bounds__(256) void prep_kernel(
    const float* __restrict__ hs, const float* __restrict__ lnw,
    const float* __restrict__ lnb, const float* __restrict__ kw,
    const float* __restrict__ qw, ushort* __restrict__ Q,
    ushort* __restrict__ Kn, ushort* __restrict__ VT) {
    __shared__ float smem[64][65];
    const int b = blockIdx.x, t = threadIdx.x;
    const int lane = t & 63, wid = t >> 6;
    if (b < NR) {
        // LayerNorm + l2-normalize row b -> Q
        const float4 v = reinterpret_cast<const float4*>(hs + (size_t)b * HD)[t];
        float s  = v.x + v.y + v.z + v.w;
        float ss = v.x*v.x + v.y*v.y + v.z*v.z + v.w*v.w;
        s = wave_sum(s); ss = wave_sum(ss);
        if (lane == 0) { smem[0][wid] = s; smem[1][wid] = ss; }
        __syncthreads();
        float st  = smem[0][0] + smem[0][1] + smem[0][2] + smem[0][3];
        float sst = smem[1][0] + smem[1][1] + smem[1][2] + smem[1][3];
        float mu   = st * (1.0f / HD);
        float var  = sst * (1.0f / HD) - mu * mu;
        float rstd = rsqrtf(var + 1e-12f);
        const float4 wv = reinterpret_cast<const float4*>(lnw)[t];
        const float4 bv = reinterpret_cast<const float4*>(lnb)[t];
        float y0 = (v.x - mu) * rstd * wv.x + bv.x;
        float y1 = (v.y - mu) * rstd * wv.y + bv.y;
        float y2 = (v.z - mu) * rstd * wv.z + bv.z;
        float y3 = (v.w - mu) * rstd * wv.w + bv.w;
        float n2 = wave_sum(y0*y0 + y1*y1 + y2*y2 + y3*y3);
        if (lane == 0) smem[2][wid] = n2;
        __syncthreads();
        float nt2 = smem[2][0] + smem[2][1] + smem[2][2] + smem[2][3];
        float sc = 1.0f / fmaxf(sqrtf(nt2), 1e-12f);
        ushort4 o;
        o.x = f2bf(y0 * sc); o.y = f2bf(y1 * sc);
        o.z = f2bf(y2 * sc); o.w = f2bf(y3 * sc);
        reinterpret_cast<ushort4*>(Q + (size_t)b * HD)[t] = o;
    } else if (b < NR + ID) {
        // l2-normalize k_weight row -> Kn
        const int row = b - NR;
        const float4 v = reinterpret_cast<const float4*>(kw + (size_t)row * HD)[t];
        float n2 = wave_sum(v.x*v.x + v.y*v.y + v.z*v.z + v.w*v.w);
        if (lane == 0) smem[0][wid] = n2;
        __syncthreads();
        float nt2 = smem[0][0] + smem[0][1] + smem[0][2] + smem[0][3];
        float sc = 1.0f / fmaxf(sqrtf(nt2), 1e-12f);
        ushort4 o;
        o.x = f2bf(v.x * sc); o.y = f2bf(v.y * sc);
        o.z = f2bf(v.z * sc); o.w = f2bf(v.w * sc);
        reinterpret_cast<ushort4*>(Kn + (size_t)row * HD)[t] = o;
    } else {
        // transpose+cast q_weight 64x64 tile -> VT
        const int b2 = b - NR - ID;
        const int bi = (b2 & 63) * 64, bh = (b2 >> 6) * 64;
        const int r0 = t >> 4, c0 = (t & 15) << 2;
#pragma unroll
        for (int rr = 0; rr < 64; rr += 16) {
            float4 val = *reinterpret_cast<const float4*>(
                &qw[(size_t)(bi + rr + r0) * HD + bh + c0]);
            smem[rr + r0][c0 + 0] = val.x; smem[rr + r0][c0 + 1] = val.y;
            smem[rr + r0][c0 + 2] = val.z; smem[rr + r0][c0 + 3] = val.w;
        }
        __syncthreads();
#pragma unroll
        for (int rr = 0; rr < 64; rr += 16) {
            ushort4 o;
            o.x = f2bf(smem[c0 + 0][rr + r0]);
            o.y = f2bf(smem[c0 + 1][rr + r0]);
            o.z = f2bf(smem[c0 + 2][rr + r0]);
            o.w = f2bf(smem[c0 + 3][rr + r0]);
            *reinterpret_cast<ushort4*>(&VT[(size_t)(bh + rr + r0) * ID + bi + c0]) = o;
        }
    }
}

// ---------------- in-place row l2-normalize + bias ----------------
__global__ __launch_bounds__(256) void outnorm_kernel(
    float* __restrict__ X, const float* __restrict__ bias) {
    __shared__ float red2[4];
    const int row = blockIdx.x, t = threadIdx.x;
    const int lane = t & 63, wid = t >> 6;
    float4 v = reinterpret_cast<float4*>(X + (size_t)row * HD)[t];
    float n2 = wave_sum(v.x*v.x + v.y*v.y + v.z*v.z + v.w*v.w);
    if (lane == 0) red2[wid] = n2;
    __syncthreads();
    float nt = red2[0] + red2[1] + red2[2] + red2[3];
    float sc = 1.0f / fmaxf(sqrtf(nt), 1e-12f);
    const float4 bv = reinterpret_cast<const float4*>(bias)[t];
    float4 o;
    o.x = v.x * sc + bv.x; o.y = v.y * sc + bv.y;
    o.z = v.z * sc + bv.z; o.w = v.w * sc + bv.w;
    reinterpret_cast<float4*>(X + (size_t)row * HD)[t] = o;
}

extern "C" void kernel_launch(void* const* d_in, const int* in_sizes, int n_in,
                              void* d_out, int out_size, void* d_ws, size_t ws_size,
                              hipStream_t stream) {
    const float* hs   = (const float*)d_in[0];  // hidden_states [4,2048,1024]
    const float* lnw  = (const float*)d_in[1];  // ln_weight [1024]
    const float* lnb  = (const float*)d_in[2];  // ln_bias [1024]
    const float* kw   = (const float*)d_in[3];  // k_weight [4096,1024]
    const float* qw   = (const float*)d_in[4];  // q_weight [4096,1024]
    const float* bias = (const float*)d_in[5];  // bias [1024]
    float* out = (float*)d_out;

    char* ws = (char*)d_ws;
    ushort* Q    = (ushort*)(ws);                                  // 16 MiB
    ushort* Kn   = (ushort*)(ws + (size_t)16777216);               //  8 MiB
    ushort* VT   = (ushort*)(ws + (size_t)16777216 + 8388608);     //  8 MiB
    ushort* Bmat = (ushort*)(ws + (size_t)16777216 + 2 * 8388608); // 64 MiB

    // merged prep: 8192 LN rows + 4096 K rows + 1024 transpose tiles
    prep_kernel<<<NR + ID + 1024, 256, 0, stream>>>(hs, lnw, lnb, kw, qw, Q, Kn, VT);
    // GEMM1: [8192,1024] x [4096,1024]^T -> act -> Bmat bf16 [8192,4096]
    //        128x128 BK=64 double-buffered, 2 blk/CU; grid 2048 = 8*32*8
    gemm1w_kernel<<<(NR / 128) * (ID / 128), 256, 0, stream>>>(
        Q, Kn, Bmat, ID, HD, HD / 64);
    // GEMM2: [8192,4096] x [1024,4096]^T -> out f32 [8192,1024]
    gemm8p_kernel<1, 0><<<(NR / 256) * (HD / 128), 512, 0, stream>>>(
        Bmat, VT, (void*)out, HD, ID, ID / 64);
    outnorm_kernel<<<NR, 256, 0, stream>>>(out, bias);
}

// Round 13
// 202.781 us; speedup vs baseline: 1.0491x; 1.0158x over previous
//
#include <hip/hip_runtime.h>

#define HD 1024
#define ID 4096
#define NR 8192

typedef float f32x4 __attribute__((ext_vector_type(4)));
typedef __bf16 bf16x8 __attribute__((ext_vector_type(8)));

__device__ inline ushort f2bf(float f) {
    union { float f; unsigned u; } v; v.f = f;
    unsigned u = v.u;
    unsigned r = (u + 0x7fffu + ((u >> 16) & 1u)) >> 16;  // RNE
    return (ushort)r;
}

__device__ inline float wave_sum(float v) {
#pragma unroll
    for (int o = 32; o > 0; o >>= 1) v += __shfl_xor(v, o, 64);
    return v;
}

template <int N> __device__ __forceinline__ void vmw() {
    static_assert(N >= 0 && N <= 4, "vmcnt");
    if constexpr (N == 0) asm volatile("s_waitcnt vmcnt(0)" ::: "memory");
    else if constexpr (N == 1) asm volatile("s_waitcnt vmcnt(1)" ::: "memory");
    else if constexpr (N == 2) asm volatile("s_waitcnt vmcnt(2)" ::: "memory");
    else if constexpr (N == 3) asm volatile("s_waitcnt vmcnt(3)" ::: "memory");
    else asm volatile("s_waitcnt vmcnt(4)" ::: "memory");
}
__device__ __forceinline__ void barrier_() {
    __builtin_amdgcn_sched_barrier(0);
    __builtin_amdgcn_s_barrier();
    __builtin_amdgcn_sched_barrier(0);
}
__device__ __forceinline__ void lgk0_() {
    asm volatile("s_waitcnt lgkmcnt(0)" ::: "memory");
    __builtin_amdgcn_sched_barrier(0);
}

// YOSO activation: t = 1 - acos(s)/pi via A&S 4.4.45 (|err| <= 6.7e-5 rad), out t^9.
__device__ __forceinline__ float yoso_act(float v) {
    float s = fminf(fmaxf(v, -0.999999f), 0.999999f);
    float a = fabsf(s);
    float p = 0.49998557f + a * (-0.06751706f + a * (0.02363794f - a * 0.00596170f));
    float q = sqrtf(1.0f - a) * p;           // acos(|s|)/pi
    float tt = (s >= 0.0f) ? 1.0f - q : q;
    float t2 = tt * tt, t4 = t2 * t2, t8 = t4 * t4;
    return t8 * tt;
}

// ======== GEMM1: R10's 2-barrier 128x128 (4 blk/CU, swizzled) + CONVOY-BREAK stagger ========
// Co-resident blocks (rnd = bid>>8 in {0..3}) phase-shifted by ~slot*500 cy at start so
// their stage/read/MFMA phases pipeline across the CU's LDS/MFMA/L2 pipes instead of
// convoying (R12 post-mortem: wall/step = SUM of pipe times = lockstep signature).
// Grid MUST be 2048 = 8 xcd * 32 cu * 8 rnd.
__global__ __launch_bounds__(256, 4) void gemm1s_kernel(
    const ushort* __restrict__ Ap, const ushort* __restrict__ Bp,
    ushort* __restrict__ Cp, int N, int K) {
    __shared__ ushort la[128 * 64] __attribute__((aligned(16)));
    __shared__ ushort lb[128 * 64] __attribute__((aligned(16)));
    const int tid = threadIdx.x;
    const int w = tid >> 6, lane = tid & 63;
    const int bid = blockIdx.x;
    const int xcd = bid & 7, cu = (bid >> 3) & 31, rnd = bid >> 8;
    const int brow = (xcd * 8 + (cu >> 2)) * 128;   // per-XCD A footprint 2 MiB
    const int bcol = (rnd * 4 + (cu & 3)) * 128;    // per-XCD B footprint 1 MiB
    const int wr = (w >> 1) * 64;
    const int wc = (w & 1) * 64;
    f32x4 acc[4][4] = {};
    const int srow = lane >> 3;
    const int scolb = ((lane & 7) ^ (lane >> 3)) << 4;  // pre-swizzled source col (bytes)

    // convoy-break: stagger co-resident slots by ~500 cy each (s_sleep 2 = ~128 cy)
    const int slot = rnd & 3;
    for (int i = 0; i < slot * 4; ++i) asm volatile("s_sleep 2");

    for (int k0 = 0; k0 < K; k0 += 64) {
#pragma unroll
        for (int it = 0; it < 4; ++it) {
            const int rb = w * 32 + it * 8;
            const char* ga = (const char*)(Ap + (size_t)(brow + rb + srow) * K + k0) + scolb;
            const char* gb = (const char*)(Bp + (size_t)(bcol + rb + srow) * K + k0) + scolb;
            __builtin_amdgcn_global_load_lds(
                (const __attribute__((address_space(1))) void*)ga,
                (__attribute__((address_space(3))) void*)&la[rb * 64], 16, 0, 0);
            __builtin_amdgcn_global_load_lds(
                (const __attribute__((address_space(1))) void*)gb,
                (__attribute__((address_space(3))) void*)&lb[rb * 64], 16, 0, 0);
        }
        __syncthreads();
#pragma unroll
        for (int ks = 0; ks < 2; ++ks) {
            bf16x8 af[4], bfr[4];
            const int colb = ks * 64 + ((lane >> 4) << 4);
            const int xk = (lane & 7) << 4;
#pragma unroll
            for (int m = 0; m < 4; ++m)
                af[m] = *(const bf16x8*)((const char*)la +
                                         (wr + m * 16 + (lane & 15)) * 128 + (colb ^ xk));
#pragma unroll
            for (int n = 0; n < 4; ++n)
                bfr[n] = *(const bf16x8*)((const char*)lb +
                                          (wc + n * 16 + (lane & 15)) * 128 + (colb ^ xk));
#pragma unroll
            for (int m = 0; m < 4; ++m)
#pragma unroll
                for (int n = 0; n < 4; ++n)
                    acc[m][n] = __builtin_amdgcn_mfma_f32_16x16x32_bf16(
                        af[m], bfr[n], acc[m][n], 0, 0, 0);
        }
        __syncthreads();
    }
    // epilogue: in-register act, direct ushort stores (16-lane groups = 32-B segments)
    const int crow0 = brow + wr + ((lane >> 4) << 2);
    const int ccol0 = bcol + wc + (lane & 15);
#pragma unroll
    for (int m = 0; m < 4; ++m)
#pragma unroll
        for (int n = 0; n < 4; ++n)
#pragma unroll
            for (int r = 0; r < 4; ++r) {
                int row = crow0 + m * 16 + r;
                int col = ccol0 + n * 16;
                Cp[(size_t)row * N + col] = f2bf(yoso_act(acc[m][n][r]));
            }
}

// ================= GEMM2: proven 8-phase 256x128 (ACT=0, f32 out) ==========
template <int NW, int ACT>
__global__ __launch_bounds__(512, 2) void gemm8p_kernel(
    const ushort* __restrict__ Ap, const ushort* __restrict__ Bp,
    void* __restrict__ Cv, int N, int K, int nt) {
    __shared__ char lds[131072] __attribute__((aligned(16)));
    const int tid = threadIdx.x;
    const int w = tid >> 6, l = tid & 63;
    const int wm = w >> 2, wn = w & 3;
    const int bid = blockIdx.x;
    const int swz = (bid & 7) * ((int)gridDim.x >> 3) + (bid >> 3);
    const int brow = (swz & 31) * 256;
    const int bcol = (swz >> 5) * (128 * NW);
    const int colsw = ((l & 7) ^ (l >> 3)) << 4;

    f32x4 acc[8][2 * NW] = {};
    bf16x8 areg[4][2];
    bf16x8 breg[2][NW][2];

    auto sA = [&](int t, int mh) {
#pragma unroll
        for (int i = 0; i < 2; ++i) {
            int s = (w * 2 + i) * 8 + (l >> 3);
            int r = ((s >> 6) << 7) + mh * 64 + (s & 63);
            const char* src = (const char*)Ap + (((size_t)(brow + r) * K + t * 64) << 1) + colsw;
            __builtin_amdgcn_global_load_lds(
                (const __attribute__((address_space(1))) void*)src,
                (__attribute__((address_space(3))) void*)&lds[(t & 1) * 32768 + mh * 16384 +
                                                              (w * 2 + i) * 1024],
                16, 0, 0);
        }
    };
    auto sB = [&](int t, int nh) {
#pragma unroll
        for (int i = 0; i < NW; ++i) {
            constexpr int SH = (NW == 2) ? 5 : 4;
            int s = (w * NW + i) * 8 + (l >> 3);
            int r = ((s >> SH) << (SH + 1)) + nh * (16 * NW) + (s & (16 * NW - 1));
            const char* src = (const char*)Bp + (((size_t)(bcol + r) * K + t * 64) << 1) + colsw;
            __builtin_amdgcn_global_load_lds(
                (const __attribute__((address_space(1))) void*)src,
                (__attribute__((address_space(3))) void*)&lds[65536 + (t & 1) * (NW * 16384) +
                                                              nh * (NW * 8192) + (w * NW + i) * 1024],
                16, 0, 0);
        }
    };
    auto load_a = [&](int db, int mh) {
#pragma unroll
        for (int m = 0; m < 4; ++m)
#pragma unroll
            for (int ks = 0; ks < 2; ++ks) {
                int s = wm * 64 + m * 16 + (l & 15);
                areg[m][ks] = *(const bf16x8*)(lds + db * 32768 + mh * 16384 + s * 128 +
                                               ((ks * 64 + ((l >> 4) << 4)) ^ ((l & 7) << 4)));
            }
    };
    auto load_b = [&](int db, int nh) {
#pragma unroll
        for (int n = 0; n < NW; ++n)
#pragma unroll
            for (int ks = 0; ks < 2; ++ks) {
                int s = wn * (16 * NW) + n * 16 + (l & 15);
                breg[nh][n][ks] = *(const bf16x8*)(lds + 65536 + db * (NW * 16384) +
                                                   nh * (NW * 8192) + s * 128 +
                                                   ((ks * 64 + ((l >> 4) << 4)) ^ ((l & 7) << 4)));
            }
    };
    auto mma = [&](int mh, int nh) {
#pragma unroll
        for (int m = 0; m < 4; ++m)
#pragma unroll
            for (int n = 0; n < NW; ++n)
#pragma unroll
                for (int ks = 0; ks < 2; ++ks)
                    acc[mh * 4 + m][nh * NW + n] = __builtin_amdgcn_mfma_f32_16x16x32_bf16(
                        areg[m][ks], breg[nh][n][ks], acc[mh * 4 + m][nh * NW + n], 0, 0, 0);
    };

    sA(0, 0); sB(0, 0); sB(0, 1); sA(0, 1);
    vmw<3>();
    barrier_();

    for (int t = 0; t < nt; ++t) {
        const int db = t & 1;
        const bool more = (t + 1 < nt);
        load_a(db, 0); load_b(db, 0);
        if (more) sA(t + 1, 0);
        barrier_(); lgk0_();
        __builtin_amdgcn_s_setprio(1); mma(0, 0); __builtin_amdgcn_s_setprio(0);
        __builtin_amdgcn_sched_barrier(0);
        if (more) vmw<4>(); else vmw<2>();
        barrier_();
        load_b(db, 1);
        if (more) sB(t + 1, 0);
        barrier_(); lgk0_();
        __builtin_amdgcn_s_setprio(1); mma(0, 1); __builtin_amdgcn_s_setprio(0);
        __builtin_amdgcn_sched_barrier(0);
        if (more) vmw<3>(); else vmw<0>();
        barrier_();
        load_a(db, 1);
        if (more) sB(t + 1, 1);
        barrier_(); lgk0_();
        __builtin_amdgcn_s_setprio(1); mma(1, 1); __builtin_amdgcn_s_setprio(0);
        barrier_();
        if (more) sA(t + 1, 1);
        barrier_();
        __builtin_amdgcn_s_setprio(1); mma(1, 0); __builtin_amdgcn_s_setprio(0);
        __builtin_amdgcn_sched_barrier(0);
        if (more) vmw<3>();
        barrier_();
    }

    char* wsl = lds + w * 16384;
    constexpr int E = ACT ? 2 : 4;
    constexpr int BPR = NW * 32 * E;
    constexpr int LPR = BPR / 16;
    constexpr int RPI = 64 / LPR;
#pragma unroll
    for (int m = 0; m < 8; ++m)
#pragma unroll
        for (int n = 0; n < 2 * NW; ++n)
#pragma unroll
            for (int r = 0; r < 4; ++r) {
                int row = m * 16 + ((l >> 4) << 2) + r;
                int colb = (n * 16 + (l & 15)) * E;
                float v = acc[m][n][r];
                if (ACT) {
                    *(ushort*)(wsl + row * 128 + (colb ^ ((row & 7) << 4))) = f2bf(yoso_act(v));
                } else {
                    *(float*)(wsl + row * 128 + (colb ^ ((row & 7) << 4))) = v;
                }
            }
    asm volatile("s_waitcnt lgkmcnt(0)" ::: "memory");
#pragma unroll
    for (int it = 0; it < 2 * LPR; ++it) {
        int row = it * RPI + l / LPR;
        int cb = (l % LPR) * 16;
        uint4 d = *(const uint4*)(wsl + row * 128 + (cb ^ ((row & 7) << 4)));
        int grow = brow + wm * 128 + row;
        size_t off = ((size_t)grow * N + (bcol + wn * (NW * 32))) * E + cb;
        *(uint4*)((char*)Cv + off) = d;
    }
}

// ---------------- Merged prep: LN+qnorm rows | knorm rows | q_weight transpose ----------------
__global__ __launch_bounds__(256) void prep_kernel(
    const float* __restrict__ hs, const float* __restrict__ lnw,
    const float* __restrict__ lnb, const float* __restrict__ kw,
    const float* __restrict__ qw, ushort* __restrict__ Q,
    ushort* __restrict__ Kn, ushort* __restrict__ VT) {
    __shared__ float smem[64][65];
    const int b = blockIdx.x, t = threadIdx.x;
    const int lane = t & 63, wid = t >> 6;
    if (b < NR) {
        const float4 v = reinterpret_cast<const float4*>(hs + (size_t)b * HD)[t];
        float s  = v.x + v.y + v.z + v.w;
        float ss = v.x*v.x + v.y*v.y + v.z*v.z + v.w*v.w;
        s = wave_sum(s); ss = wave_sum(ss);
        if (lane == 0) { smem[0][wid] = s; smem[1][wid] = ss; }
        __syncthreads();
        float st  = smem[0][0] + smem[0][1] + smem[0][2] + smem[0][3];
        float sst = smem[1][0] + smem[1][1] + smem[1][2] + smem[1][3];
        float mu   = st * (1.0f / HD);
        float var  = sst * (1.0f / HD) - mu * mu;
        float rstd = rsqrtf(var + 1e-12f);
        const float4 wv = reinterpret_cast<const float4*>(lnw)[t];
        const float4 bv = reinterpret_cast<const float4*>(lnb)[t];
        float y0 = (v.x - mu) * rstd * wv.x + bv.x;
        float y1 = (v.y - mu) * rstd * wv.y + bv.y;
        float y2 = (v.z - mu) * rstd * wv.z + bv.z;
        float y3 = (v.w - mu) * rstd * wv.w + bv.w;
        float n2 = wave_sum(y0*y0 + y1*y1 + y2*y2 + y3*y3);
        if (lane == 0) smem[2][wid] = n2;
        __syncthreads();
        float nt2 = smem[2][0] + smem[2][1] + smem[2][2] + smem[2][3];
        float sc = 1.0f / fmaxf(sqrtf(nt2), 1e-12f);
        ushort4 o;
        o.x = f2bf(y0 * sc); o.y = f2bf(y1 * sc);
        o.z = f2bf(y2 * sc); o.w = f2bf(y3 * sc);
        reinterpret_cast<ushort4*>(Q + (size_t)b * HD)[t] = o;
    } else if (b < NR + ID) {
        const int row = b - NR;
        const float4 v = reinterpret_cast<const float4*>(kw + (size_t)row * HD)[t];
        float n2 = wave_sum(v.x*v.x + v.y*v.y + v.z*v.z + v.w*v.w);
        if (lane == 0) smem[0][wid] = n2;
        __syncthreads();
        float nt2 = smem[0][0] + smem[0][1] + smem[0][2] + smem[0][3];
        float sc = 1.0f / fmaxf(sqrtf(nt2), 1e-12f);
        ushort4 o;
        o.x = f2bf(v.x * sc); o.y = f2bf(v.y * sc);
        o.z = f2bf(v.z * sc); o.w = f2bf(v.w * sc);
        reinterpret_cast<ushort4*>(Kn + (size_t)row * HD)[t] = o;
    } else {
        const int b2 = b - NR - ID;
        const int bi = (b2 & 63) * 64, bh = (b2 >> 6) * 64;
        const int r0 = t >> 4, c0 = (t & 15) << 2;
#pragma unroll
        for (int rr = 0; rr < 64; rr += 16) {
            float4 val = *reinterpret_cast<const float4*>(
                &qw[(size_t)(bi + rr + r0) * HD + bh + c0]);
            smem[rr + r0][c0 + 0] = val.x; smem[rr + r0][c0 + 1] = val.y;
            smem[rr + r0][c0 + 2] = val.z; smem[rr + r0][c0 + 3] = val.w;
        }
        __syncthreads();
#pragma unroll
        for (int rr = 0; rr < 64; rr += 16) {
            ushort4 o;
            o.x = f2bf(smem[c0 + 0][rr + r0]);
            o.y = f2bf(smem[c0 + 1][rr + r0]);
            o.z = f2bf(smem[c0 + 2][rr + r0]);
            o.w = f2bf(smem[c0 + 3][rr + r0]);
            *reinterpret_cast<ushort4*>(&VT[(size_t)(bh + rr + r0) * ID + bi + c0]) = o;
        }
    }
}

// ---------------- in-place row l2-normalize + bias ----------------
__global__ __launch_bounds__(256) void outnorm_kernel(
    float* __restrict__ X, const float* __restrict__ bias) {
    __shared__ float red2[4];
    const int row = blockIdx.x, t = threadIdx.x;
    const int lane = t & 63, wid = t >> 6;
    float4 v = reinterpret_cast<float4*>(X + (size_t)row * HD)[t];
    float n2 = wave_sum(v.x*v.x + v.y*v.y + v.z*v.z + v.w*v.w);
    if (lane == 0) red2[wid] = n2;
    __syncthreads();
    float nt = red2[0] + red2[1] + red2[2] + red2[3];
    float sc = 1.0f / fmaxf(sqrtf(nt), 1e-12f);
    const float4 bv = reinterpret_cast<const float4*>(bias)[t];
    float4 o;
    o.x = v.x * sc + bv.x; o.y = v.y * sc + bv.y;
    o.z = v.z * sc + bv.z; o.w = v.w * sc + bv.w;
    reinterpret_cast<float4*>(X + (size_t)row * HD)[t] = o;
}

extern "C" void kernel_launch(void* const* d_in, const int* in_sizes, int n_in,
                              void* d_out, int out_size, void* d_ws, size_t ws_size,
                              hipStream_t stream) {
    const float* hs   = (const float*)d_in[0];  // hidden_states [4,2048,1024]
    const float* lnw  = (const float*)d_in[1];  // ln_weight [1024]
    const float* lnb  = (const float*)d_in[2];  // ln_bias [1024]
    const float* kw   = (const float*)d_in[3];  // k_weight [4096,1024]
    const float* qw   = (const float*)d_in[4];  // q_weight [4096,1024]
    const float* bias = (const float*)d_in[5];  // bias [1024]
    float* out = (float*)d_out;

    char* ws = (char*)d_ws;
    ushort* Q    = (ushort*)(ws);                                  // 16 MiB
    ushort* Kn   = (ushort*)(ws + (size_t)16777216);               //  8 MiB
    ushort* VT   = (ushort*)(ws + (size_t)16777216 + 8388608);     //  8 MiB
    ushort* Bmat = (ushort*)(ws + (size_t)16777216 + 2 * 8388608); // 64 MiB

    // merged prep: 8192 LN rows + 4096 K rows + 1024 transpose tiles
    prep_kernel<<<NR + ID + 1024, 256, 0, stream>>>(hs, lnw, lnb, kw, qw, Q, Kn, VT);
    // GEMM1: [8192,1024] x [4096,1024]^T -> act -> Bmat bf16 [8192,4096]
    //        R10 kernel + convoy-break stagger; grid 2048 = 8*32*8
    gemm1s_kernel<<<(NR / 128) * (ID / 128), 256, 0, stream>>>(
        Q, Kn, Bmat, ID, HD);
    // GEMM2: [8192,4096] x [1024,4096]^T -> out f32 [8192,1024]
    gemm8p_kernel<1, 0><<<(NR / 256) * (HD / 128), 512, 0, stream>>>(
        Bmat, VT, (void*)out, HD, ID, ID / 64);
    outnorm_kernel<<<NR, 256, 0, stream>>>(out, bias);
}

// Round 14
// 170.389 us; speedup vs baseline: 1.2485x; 1.1901x over previous
//
#include <hip/hip_runtime.h>

#define HD 1024
#define ID 4096
#define NR 8192

typedef float f32x4 __attribute__((ext_vector_type(4)));
typedef __bf16 bf16x8 __attribute__((ext_vector_type(8)));
typedef int i32x8 __attribute__((ext_vector_type(8)));

__device__ inline ushort f2bf(float f) {
    union { float f; unsigned u; } v; v.f = f;
    unsigned u = v.u;
    unsigned r = (u + 0x7fffu + ((u >> 16) & 1u)) >> 16;  // RNE
    return (ushort)r;
}

__device__ inline float wave_sum(float v) {
#pragma unroll
    for (int o = 32; o > 0; o >>= 1) v += __shfl_xor(v, o, 64);
    return v;
}

template <int N> __device__ __forceinline__ void vmw() {
    static_assert(N >= 0 && N <= 4, "vmcnt");
    if constexpr (N == 0) asm volatile("s_waitcnt vmcnt(0)" ::: "memory");
    else if constexpr (N == 1) asm volatile("s_waitcnt vmcnt(1)" ::: "memory");
    else if constexpr (N == 2) asm volatile("s_waitcnt vmcnt(2)" ::: "memory");
    else if constexpr (N == 3) asm volatile("s_waitcnt vmcnt(3)" ::: "memory");
    else asm volatile("s_waitcnt vmcnt(4)" ::: "memory");
}
__device__ __forceinline__ void barrier_() {
    __builtin_amdgcn_sched_barrier(0);
    __builtin_amdgcn_s_barrier();
    __builtin_amdgcn_sched_barrier(0);
}
__device__ __forceinline__ void lgk0_() {
    asm volatile("s_waitcnt lgkmcnt(0)" ::: "memory");
    __builtin_amdgcn_sched_barrier(0);
}

// YOSO activation: t = 1 - acos(s)/pi via A&S 4.4.45 (|err| <= 6.7e-5 rad), out t^9.
__device__ __forceinline__ float yoso_act(float v) {
    float s = fminf(fmaxf(v, -0.999999f), 0.999999f);
    float a = fabsf(s);
    float p = 0.49998557f + a * (-0.06751706f + a * (0.02363794f - a * 0.00596170f));
    float q = sqrtf(1.0f - a) * p;           // acos(|s|)/pi
    float tt = (s >= 0.0f) ? 1.0f - q : q;
    float t2 = tt * tt, t4 = t2 * t2, t8 = t4 * t4;
    return t8 * tt;
}

// ======== GEMM1: MX-fp8 e4m3, 128x128 tile, BK=128, 16x16x128 scaled MFMA ========
// R10's proven 2-barrier structure + swizzle, dtype fp8: staging bytes halve, MFMA
// instruction count halves at 2x rate. Inputs pre-scaled x16 at conversion; scales
// here = 1.0 (0x7F uniform, op_sel moot); epilogue multiplies acc by 1/256.
// Frag (16x16x128): lane holds A[row=lane&15][k=(lane>>4)*32 .. +32) = 8 dwords.
// LDS: [128 rows][128 B], slot-XOR key (row&7)<<4; source pre-swizzled (rule 21).
// Grid MUST be 2048 = 8 xcd * 32 cu * 8 rnd (banded map).
__global__ __launch_bounds__(256, 3) void gemm1f_kernel(
    const unsigned char* __restrict__ Ap, const unsigned char* __restrict__ Bp,
    ushort* __restrict__ Cp, int N, int K) {
    __shared__ unsigned char la[128 * 128] __attribute__((aligned(16)));
    __shared__ unsigned char lb[128 * 128] __attribute__((aligned(16)));
    const int tid = threadIdx.x;
    const int w = tid >> 6, lane = tid & 63;
    const int bid = blockIdx.x;
    const int xcd = bid & 7, cu = (bid >> 3) & 31, rnd = bid >> 8;
    const int brow = (xcd * 8 + (cu >> 2)) * 128;   // per-XCD A footprint 1 MiB (fp8)
    const int bcol = (rnd * 4 + (cu & 3)) * 128;
    const int wr = (w >> 1) * 64;
    const int wc = (w & 1) * 64;
    f32x4 acc[4][4] = {};
    const int srow = lane >> 3;
    const int scolb = ((lane & 7) ^ (lane >> 3)) << 4;  // pre-swizzled source slot (bytes)

    for (int k0 = 0; k0 < K; k0 += 128) {   // K in BYTES (=elements, fp8); 8 steps
#pragma unroll
        for (int it = 0; it < 4; ++it) {
            const int rb = w * 32 + it * 8;
            const unsigned char* ga = Ap + (size_t)(brow + rb + srow) * K + k0 + scolb;
            const unsigned char* gb = Bp + (size_t)(bcol + rb + srow) * K + k0 + scolb;
            __builtin_amdgcn_global_load_lds(
                (const __attribute__((address_space(1))) void*)ga,
                (__attribute__((address_space(3))) void*)&la[rb * 128], 16, 0, 0);
            __builtin_amdgcn_global_load_lds(
                (const __attribute__((address_space(1))) void*)gb,
                (__attribute__((address_space(3))) void*)&lb[rb * 128], 16, 0, 0);
        }
        __syncthreads();
        i32x8 af[4], bfr[4];
        const int base = (lane >> 4) << 5;  // k-chunk byte base: 0,32,64,96
#pragma unroll
        for (int m = 0; m < 4; ++m) {
            const int row = wr + m * 16 + (lane & 15);
            const int key = (row & 7) << 4;
            const uint4 lo = *(const uint4*)(la + row * 128 + (base ^ key));
            const uint4 hi = *(const uint4*)(la + row * 128 + ((base + 16) ^ key));
            af[m] = (i32x8){(int)lo.x, (int)lo.y, (int)lo.z, (int)lo.w,
                            (int)hi.x, (int)hi.y, (int)hi.z, (int)hi.w};
        }
#pragma unroll
        for (int n = 0; n < 4; ++n) {
            const int row = wc + n * 16 + (lane & 15);
            const int key = (row & 7) << 4;
            const uint4 lo = *(const uint4*)(lb + row * 128 + (base ^ key));
            const uint4 hi = *(const uint4*)(lb + row * 128 + ((base + 16) ^ key));
            bfr[n] = (i32x8){(int)lo.x, (int)lo.y, (int)lo.z, (int)lo.w,
                             (int)hi.x, (int)hi.y, (int)hi.z, (int)hi.w};
        }
#pragma unroll
        for (int m = 0; m < 4; ++m)
#pragma unroll
            for (int n = 0; n < 4; ++n)
                acc[m][n] = __builtin_amdgcn_mfma_scale_f32_16x16x128_f8f6f4(
                    af[m], bfr[n], acc[m][n], 0, 0,       // cbsz=0 (fp8), blgp=0 (fp8)
                    0, 0x7F7F7F7F, 0, 0x7F7F7F7F);        // scales = 1.0 (uniform)
        __syncthreads();
    }
    // epilogue: undo the 16x16 input prescale (1/256), act, direct ushort stores
    const int crow0 = brow + wr + ((lane >> 4) << 2);
    const int ccol0 = bcol + wc + (lane & 15);
#pragma unroll
    for (int m = 0; m < 4; ++m)
#pragma unroll
        for (int n = 0; n < 4; ++n)
#pragma unroll
            for (int r = 0; r < 4; ++r) {
                int row = crow0 + m * 16 + r;
                int col = ccol0 + n * 16;
                Cp[(size_t)row * N + col] =
                    f2bf(yoso_act(acc[m][n][r] * 0.00390625f));
            }
}

// ================= GEMM2: proven 8-phase 256x128 (ACT=0, f32 out) ==========
template <int NW, int ACT>
__global__ __launch_bounds__(512, 2) void gemm8p_kernel(
    const ushort* __restrict__ Ap, const ushort* __restrict__ Bp,
    void* __restrict__ Cv, int N, int K, int nt) {
    __shared__ char lds[131072] __attribute__((aligned(16)));
    const int tid = threadIdx.x;
    const int w = tid >> 6, l = tid & 63;
    const int wm = w >> 2, wn = w & 3;
    const int bid = blockIdx.x;
    const int swz = (bid & 7) * ((int)gridDim.x >> 3) + (bid >> 3);
    const int brow = (swz & 31) * 256;
    const int bcol = (swz >> 5) * (128 * NW);
    const int colsw = ((l & 7) ^ (l >> 3)) << 4;

    f32x4 acc[8][2 * NW] = {};
    bf16x8 areg[4][2];
    bf16x8 breg[2][NW][2];

    auto sA = [&](int t, int mh) {
#pragma unroll
        for (int i = 0; i < 2; ++i) {
            int s = (w * 2 + i) * 8 + (l >> 3);
            int r = ((s >> 6) << 7) + mh * 64 + (s & 63);
            const char* src = (const char*)Ap + (((size_t)(brow + r) * K + t * 64) << 1) + colsw;
            __builtin_amdgcn_global_load_lds(
                (const __attribute__((address_space(1))) void*)src,
                (__attribute__((address_space(3))) void*)&lds[(t & 1) * 32768 + mh * 16384 +
                                                              (w * 2 + i) * 1024],
                16, 0, 0);
        }
    };
    auto sB = [&](int t, int nh) {
#pragma unroll
        for (int i = 0; i < NW; ++i) {
            constexpr int SH = (NW == 2) ? 5 : 4;
            int s = (w * NW + i) * 8 + (l >> 3);
            int r = ((s >> SH) << (SH + 1)) + nh * (16 * NW) + (s & (16 * NW - 1));
            const char* src = (const char*)Bp + (((size_t)(bcol + r) * K + t * 64) << 1) + colsw;
            __builtin_amdgcn_global_load_lds(
                (const __attribute__((address_space(1))) void*)src,
                (__attribute__((address_space(3))) void*)&lds[65536 + (t & 1) * (NW * 16384) +
                                                              nh * (NW * 8192) + (w * NW + i) * 1024],
                16, 0, 0);
        }
    };
    auto load_a = [&](int db, int mh) {
#pragma unroll
        for (int m = 0; m < 4; ++m)
#pragma unroll
            for (int ks = 0; ks < 2; ++ks) {
                int s = wm * 64 + m * 16 + (l & 15);
                areg[m][ks] = *(const bf16x8*)(lds + db * 32768 + mh * 16384 + s * 128 +
                                               ((ks * 64 + ((l >> 4) << 4)) ^ ((l & 7) << 4)));
            }
    };
    auto load_b = [&](int db, int nh) {
#pragma unroll
        for (int n = 0; n < NW; ++n)
#pragma unroll
            for (int ks = 0; ks < 2; ++ks) {
                int s = wn * (16 * NW) + n * 16 + (l & 15);
                breg[nh][n][ks] = *(const bf16x8*)(lds + 65536 + db * (NW * 16384) +
                                                   nh * (NW * 8192) + s * 128 +
                                                   ((ks * 64 + ((l >> 4) << 4)) ^ ((l & 7) << 4)));
            }
    };
    auto mma = [&](int mh, int nh) {
#pragma unroll
        for (int m = 0; m < 4; ++m)
#pragma unroll
            for (int n = 0; n < NW; ++n)
#pragma unroll
                for (int ks = 0; ks < 2; ++ks)
                    acc[mh * 4 + m][nh * NW + n] = __builtin_amdgcn_mfma_f32_16x16x32_bf16(
                        areg[m][ks], breg[nh][n][ks], acc[mh * 4 + m][nh * NW + n], 0, 0, 0);
    };

    sA(0, 0); sB(0, 0); sB(0, 1); sA(0, 1);
    vmw<3>();
    barrier_();

    for (int t = 0; t < nt; ++t) {
        const int db = t & 1;
        const bool more = (t + 1 < nt);
        load_a(db, 0); load_b(db, 0);
        if (more) sA(t + 1, 0);
        barrier_(); lgk0_();
        __builtin_amdgcn_s_setprio(1); mma(0, 0); __builtin_amdgcn_s_setprio(0);
        __builtin_amdgcn_sched_barrier(0);
        if (more) vmw<4>(); else vmw<2>();
        barrier_();
        load_b(db, 1);
        if (more) sB(t + 1, 0);
        barrier_(); lgk0_();
        __builtin_amdgcn_s_setprio(1); mma(0, 1); __builtin_amdgcn_s_setprio(0);
        __builtin_amdgcn_sched_barrier(0);
        if (more) vmw<3>(); else vmw<0>();
        barrier_();
        load_a(db, 1);
        if (more) sB(t + 1, 1);
        barrier_(); lgk0_();
        __builtin_amdgcn_s_setprio(1); mma(1, 1); __builtin_amdgcn_s_setprio(0);
        barrier_();
        if (more) sA(t + 1, 1);
        barrier_();
        __builtin_amdgcn_s_setprio(1); mma(1, 0); __builtin_amdgcn_s_setprio(0);
        __builtin_amdgcn_sched_barrier(0);
        if (more) vmw<3>();
        barrier_();
    }

    char* wsl = lds + w * 16384;
    constexpr int E = ACT ? 2 : 4;
    constexpr int BPR = NW * 32 * E;
    constexpr int LPR = BPR / 16;
    constexpr int RPI = 64 / LPR;
#pragma unroll
    for (int m = 0; m < 8; ++m)
#pragma unroll
        for (int n = 0; n < 2 * NW; ++n)
#pragma unroll
            for (int r = 0; r < 4; ++r) {
                int row = m * 16 + ((l >> 4) << 2) + r;
                int colb = (n * 16 + (l & 15)) * E;
                float v = acc[m][n][r];
                if (ACT) {
                    *(ushort*)(wsl + row * 128 + (colb ^ ((row & 7) << 4))) = f2bf(yoso_act(v));
                } else {
                    *(float*)(wsl + row * 128 + (colb ^ ((row & 7) << 4))) = v;
                }
            }
    asm volatile("s_waitcnt lgkmcnt(0)" ::: "memory");
#pragma unroll
    for (int it = 0; it < 2 * LPR; ++it) {
        int row = it * RPI + l / LPR;
        int cb = (l % LPR) * 16;
        uint4 d = *(const uint4*)(wsl + row * 128 + (cb ^ ((row & 7) << 4)));
        int grow = brow + wm * 128 + row;
        size_t off = ((size_t)grow * N + (bcol + wn * (NW * 32))) * E + cb;
        *(uint4*)((char*)Cv + off) = d;
    }
}

// ---------------- Merged prep: LN+qnorm -> fp8 | knorm -> fp8 | q_weight transpose -> bf16 ----------------
__global__ __launch_bounds__(256) void prep_kernel(
    const float* __restrict__ hs, const float* __restrict__ lnw,
    const float* __restrict__ lnb, const float* __restrict__ kw,
    const float* __restrict__ qw, unsigned char* __restrict__ Qf,
    unsigned char* __restrict__ Kf, ushort* __restrict__ VT) {
    __shared__ float smem[64][65];
    const int b = blockIdx.x, t = threadIdx.x;
    const int lane = t & 63, wid = t >> 6;
    if (b < NR) {
        const float4 v = reinterpret_cast<const float4*>(hs + (size_t)b * HD)[t];
        float s  = v.x + v.y + v.z + v.w;
        float ss = v.x*v.x + v.y*v.y + v.z*v.z + v.w*v.w;
        s = wave_sum(s); ss = wave_sum(ss);
        if (lane == 0) { smem[0][wid] = s; smem[1][wid] = ss; }
        __syncthreads();
        float st  = smem[0][0] + smem[0][1] + smem[0][2] + smem[0][3];
        float sst = smem[1][0] + smem[1][1] + smem[1][2] + smem[1][3];
        float mu   = st * (1.0f / HD);
        float var  = sst * (1.0f / HD) - mu * mu;
        float rstd = rsqrtf(var + 1e-12f);
        const float4 wv = reinterpret_cast<const float4*>(lnw)[t];
        const float4 bv = reinterpret_cast<const float4*>(lnb)[t];
        float y0 = (v.x - mu) * rstd * wv.x + bv.x;
        float y1 = (v.y - mu) * rstd * wv.y + bv.y;
        float y2 = (v.z - mu) * rstd * wv.z + bv.z;
        float y3 = (v.w - mu) * rstd * wv.w + bv.w;
        float n2 = wave_sum(y0*y0 + y1*y1 + y2*y2 + y3*y3);
        if (lane == 0) smem[2][wid] = n2;
        __syncthreads();
        float nt2 = smem[2][0] + smem[2][1] + smem[2][2] + smem[2][3];
        float sc = 16.0f / fmaxf(sqrtf(nt2), 1e-12f);   // x16 prescale for fp8
        int r = __builtin_amdgcn_cvt_pk_fp8_f32(y0 * sc, y1 * sc, 0, false);
        r = __builtin_amdgcn_cvt_pk_fp8_f32(y2 * sc, y3 * sc, r, true);
        reinterpret_cast<int*>(Qf + (size_t)b * HD)[t] = r;
    } else if (b < NR + ID) {
        const int row = b - NR;
        const float4 v = reinterpret_cast<const float4*>(kw + (size_t)row * HD)[t];
        float n2 = wave_sum(v.x*v.x + v.y*v.y + v.z*v.z + v.w*v.w);
        if (lane == 0) smem[0][wid] = n2;
        __syncthreads();
        float nt2 = smem[0][0] + smem[0][1] + smem[0][2] + smem[0][3];
        float sc = 16.0f / fmaxf(sqrtf(nt2), 1e-12f);   // x16 prescale for fp8
        int r = __builtin_amdgcn_cvt_pk_fp8_f32(v.x * sc, v.y * sc, 0, false);
        r = __builtin_amdgcn_cvt_pk_fp8_f32(v.z * sc, v.w * sc, r, true);
        reinterpret_cast<int*>(Kf + (size_t)row * HD)[t] = r;
    } else {
        const int b2 = b - NR - ID;
        const int bi = (b2 & 63) * 64, bh = (b2 >> 6) * 64;
        const int r0 = t >> 4, c0 = (t & 15) << 2;
#pragma unroll
        for (int rr = 0; rr < 64; rr += 16) {
            float4 val = *reinterpret_cast<const float4*>(
                &qw[(size_t)(bi + rr + r0) * HD + bh + c0]);
            smem[rr + r0][c0 + 0] = val.x; smem[rr + r0][c0 + 1] = val.y;
            smem[rr + r0][c0 + 2] = val.z; smem[rr + r0][c0 + 3] = val.w;
        }
        __syncthreads();
#pragma unroll
        for (int rr = 0; rr < 64; rr += 16) {
            ushort4 o;
            o.x = f2bf(smem[c0 + 0][rr + r0]);
            o.y = f2bf(smem[c0 + 1][rr + r0]);
            o.z = f2bf(smem[c0 + 2][rr + r0]);
            o.w = f2bf(smem[c0 + 3][rr + r0]);
            *reinterpret_cast<ushort4*>(&VT[(size_t)(bh + rr + r0) * ID + bi + c0]) = o;
        }
    }
}

// ---------------- in-place row l2-normalize + bias ----------------
__global__ __launch_bounds__(256) void outnorm_kernel(
    float* __restrict__ X, const float* __restrict__ bias) {
    __shared__ float red2[4];
    const int row = blockIdx.x, t = threadIdx.x;
    const int lane = t & 63, wid = t >> 6;
    float4 v = reinterpret_cast<float4*>(X + (size_t)row * HD)[t];
    float n2 = wave_sum(v.x*v.x + v.y*v.y + v.z*v.z + v.w*v.w);
    if (lane == 0) red2[wid] = n2;
    __syncthreads();
    float nt = red2[0] + red2[1] + red2[2] + red2[3];
    float sc = 1.0f / fmaxf(sqrtf(nt), 1e-12f);
    const float4 bv = reinterpret_cast<const float4*>(bias)[t];
    float4 o;
    o.x = v.x * sc + bv.x; o.y = v.y * sc + bv.y;
    o.z = v.z * sc + bv.z; o.w = v.w * sc + bv.w;
    reinterpret_cast<float4*>(X + (size_t)row * HD)[t] = o;
}

extern "C" void kernel_launch(void* const* d_in, const int* in_sizes, int n_in,
                              void* d_out, int out_size, void* d_ws, size_t ws_size,
                              hipStream_t stream) {
    const float* hs   = (const float*)d_in[0];  // hidden_states [4,2048,1024]
    const float* lnw  = (const float*)d_in[1];  // ln_weight [1024]
    const float* lnb  = (const float*)d_in[2];  // ln_bias [1024]
    const float* kw   = (const float*)d_in[3];  // k_weight [4096,1024]
    const float* qw   = (const float*)d_in[4];  // q_weight [4096,1024]
    const float* bias = (const float*)d_in[5];  // bias [1024]
    float* out = (float*)d_out;

    char* ws = (char*)d_ws;
    unsigned char* Qf = (unsigned char*)(ws);                       //  8 MiB fp8
    unsigned char* Kf = (unsigned char*)(ws + (size_t)8388608);     //  4 MiB fp8
    ushort* VT   = (ushort*)(ws + (size_t)12582912);                //  8 MiB bf16
    ushort* Bmat = (ushort*)(ws + (size_t)20971520);                // 64 MiB bf16

    // merged prep: 8192 LN rows (fp8) + 4096 K rows (fp8) + 1024 transpose tiles (bf16)
    prep_kernel<<<NR + ID + 1024, 256, 0, stream>>>(hs, lnw, lnb, kw, qw, Qf, Kf, VT);
    // GEMM1: MX-fp8 [8192,1024] x [4096,1024]^T -> act -> Bmat bf16 [8192,4096]
    //        128x128 tile, BK=128, 16x16x128 scaled MFMA; grid 2048 = 8*32*8
    gemm1f_kernel<<<(NR / 128) * (ID / 128), 256, 0, stream>>>(
        Qf, Kf, Bmat, ID, HD);
    // GEMM2: [8192,4096] x [1024,4096]^T -> out f32 [8192,1024] (bf16 MFMA)
    gemm8p_kernel<1, 0><<<(NR / 256) * (HD / 128), 512, 0, stream>>>(
        Bmat, VT, (void*)out, HD, ID, ID / 64);
    outnorm_kernel<<<NR, 256, 0, stream>>>(out, bias);
}

// Round 15
// 165.630 us; speedup vs baseline: 1.2844x; 1.0287x over previous
//
#include <hip/hip_runtime.h>

#define HD 1024
#define ID 4096
#define NR 8192

typedef float f32x4 __attribute__((ext_vector_type(4)));
typedef __bf16 bf16x8 __attribute__((ext_vector_type(8)));
typedef int i32x8 __attribute__((ext_vector_type(8)));

__device__ inline ushort f2bf(float f) {
    union { float f; unsigned u; } v; v.f = f;
    unsigned u = v.u;
    unsigned r = (u + 0x7fffu + ((u >> 16) & 1u)) >> 16;  // RNE
    return (ushort)r;
}

__device__ inline float wave_sum(float v) {
#pragma unroll
    for (int o = 32; o > 0; o >>= 1) v += __shfl_xor(v, o, 64);
    return v;
}

template <int N> __device__ __forceinline__ void vmw() {
    static_assert(N >= 0 && N <= 4, "vmcnt");
    if constexpr (N == 0) asm volatile("s_waitcnt vmcnt(0)" ::: "memory");
    else if constexpr (N == 1) asm volatile("s_waitcnt vmcnt(1)" ::: "memory");
    else if constexpr (N == 2) asm volatile("s_waitcnt vmcnt(2)" ::: "memory");
    else if constexpr (N == 3) asm volatile("s_waitcnt vmcnt(3)" ::: "memory");
    else asm volatile("s_waitcnt vmcnt(4)" ::: "memory");
}
__device__ __forceinline__ void barrier_() {
    __builtin_amdgcn_sched_barrier(0);
    __builtin_amdgcn_s_barrier();
    __builtin_amdgcn_sched_barrier(0);
}
__device__ __forceinline__ void lgk0_() {
    asm volatile("s_waitcnt lgkmcnt(0)" ::: "memory");
    __builtin_amdgcn_sched_barrier(0);
}

// YOSO activation: t = 1 - acos(s)/pi via A&S 4.4.45 (|err| <= 6.7e-5 rad), out t^9.
__device__ __forceinline__ float yoso_act(float v) {
    float s = fminf(fmaxf(v, -0.999999f), 0.999999f);
    float a = fabsf(s);
    float p = 0.49998557f + a * (-0.06751706f + a * (0.02363794f - a * 0.00596170f));
    float q = sqrtf(1.0f - a) * p;           // acos(|s|)/pi
    float tt = (s >= 0.0f) ? 1.0f - q : q;
    float t2 = tt * tt, t4 = t2 * t2, t8 = t4 * t4;
    return t8 * tt;
}

// ======== GEMM1: MX-fp8 e4m3, 128x128 tile, BK=128, 16x16x128 scaled MFMA ========
// R10's proven 2-barrier structure + swizzle, dtype fp8 (R14: 107 -> ~60 us).
// Grid MUST be 2048 = 8 xcd * 32 cu * 8 rnd (banded map).
__global__ __launch_bounds__(256, 3) void gemm1f_kernel(
    const unsigned char* __restrict__ Ap, const unsigned char* __restrict__ Bp,
    ushort* __restrict__ Cp, int N, int K) {
    __shared__ unsigned char la[128 * 128] __attribute__((aligned(16)));
    __shared__ unsigned char lb[128 * 128] __attribute__((aligned(16)));
    const int tid = threadIdx.x;
    const int w = tid >> 6, lane = tid & 63;
    const int bid = blockIdx.x;
    const int xcd = bid & 7, cu = (bid >> 3) & 31, rnd = bid >> 8;
    const int brow = (xcd * 8 + (cu >> 2)) * 128;   // per-XCD A footprint 1 MiB (fp8)
    const int bcol = (rnd * 4 + (cu & 3)) * 128;
    const int wr = (w >> 1) * 64;
    const int wc = (w & 1) * 64;
    f32x4 acc[4][4] = {};
    const int srow = lane >> 3;
    const int scolb = ((lane & 7) ^ (lane >> 3)) << 4;  // pre-swizzled source slot (bytes)

    for (int k0 = 0; k0 < K; k0 += 128) {   // K in BYTES (=elements, fp8); 8 steps
#pragma unroll
        for (int it = 0; it < 4; ++it) {
            const int rb = w * 32 + it * 8;
            const unsigned char* ga = Ap + (size_t)(brow + rb + srow) * K + k0 + scolb;
            const unsigned char* gb = Bp + (size_t)(bcol + rb + srow) * K + k0 + scolb;
            __builtin_amdgcn_global_load_lds(
                (const __attribute__((address_space(1))) void*)ga,
                (__attribute__((address_space(3))) void*)&la[rb * 128], 16, 0, 0);
            __builtin_amdgcn_global_load_lds(
                (const __attribute__((address_space(1))) void*)gb,
                (__attribute__((address_space(3))) void*)&lb[rb * 128], 16, 0, 0);
        }
        __syncthreads();
        i32x8 af[4], bfr[4];
        const int base = (lane >> 4) << 5;  // k-chunk byte base: 0,32,64,96
#pragma unroll
        for (int m = 0; m < 4; ++m) {
            const int row = wr + m * 16 + (lane & 15);
            const int key = (row & 7) << 4;
            const uint4 lo = *(const uint4*)(la + row * 128 + (base ^ key));
            const uint4 hi = *(const uint4*)(la + row * 128 + ((base + 16) ^ key));
            af[m] = (i32x8){(int)lo.x, (int)lo.y, (int)lo.z, (int)lo.w,
                            (int)hi.x, (int)hi.y, (int)hi.z, (int)hi.w};
        }
#pragma unroll
        for (int n = 0; n < 4; ++n) {
            const int row = wc + n * 16 + (lane & 15);
            const int key = (row & 7) << 4;
            const uint4 lo = *(const uint4*)(lb + row * 128 + (base ^ key));
            const uint4 hi = *(const uint4*)(lb + row * 128 + ((base + 16) ^ key));
            bfr[n] = (i32x8){(int)lo.x, (int)lo.y, (int)lo.z, (int)lo.w,
                             (int)hi.x, (int)hi.y, (int)hi.z, (int)hi.w};
        }
#pragma unroll
        for (int m = 0; m < 4; ++m)
#pragma unroll
            for (int n = 0; n < 4; ++n)
                acc[m][n] = __builtin_amdgcn_mfma_scale_f32_16x16x128_f8f6f4(
                    af[m], bfr[n], acc[m][n], 0, 0,       // cbsz=0 (fp8), blgp=0 (fp8)
                    0, 0x7F7F7F7F, 0, 0x7F7F7F7F);        // scales = 1.0 (uniform)
        __syncthreads();
    }
    // epilogue: undo the 16x16 input prescale (1/256), act, direct ushort stores
    const int crow0 = brow + wr + ((lane >> 4) << 2);
    const int ccol0 = bcol + wc + (lane & 15);
#pragma unroll
    for (int m = 0; m < 4; ++m)
#pragma unroll
        for (int n = 0; n < 4; ++n)
#pragma unroll
            for (int r = 0; r < 4; ++r) {
                int row = crow0 + m * 16 + r;
                int col = ccol0 + n * 16;
                Cp[(size_t)row * N + col] =
                    f2bf(yoso_act(acc[m][n][r] * 0.00390625f));
            }
}

// ================= GEMM2: 8-phase 256x128 (ACT=0, f32 out) =================
// MAP=0: flat XCD swizzle. MAP=1: XCD-banded (grid MUST be 256 = 8 xcd * 32 cu;
//        each XCD owns 4 brows x 8 bcols -> per-XCD A-band 8 MiB read once with
//        8-way concurrent sharing, B slices 4-way shared; fixes R14's 266 MB
//        FETCH from every XCD streaming the whole 64 MiB Bmat).
template <int NW, int ACT, int MAP>
__global__ __launch_bounds__(512, 2) void gemm8p_kernel(
    const ushort* __restrict__ Ap, const ushort* __restrict__ Bp,
    void* __restrict__ Cv, int N, int K, int nt) {
    __shared__ char lds[131072] __attribute__((aligned(16)));
    const int tid = threadIdx.x;
    const int w = tid >> 6, l = tid & 63;
    const int wm = w >> 2, wn = w & 3;
    const int bid = blockIdx.x;
    int brow, bcol;
    if constexpr (MAP == 1) {
        const int xcd = bid & 7, cu = bid >> 3;
        brow = (xcd * 4 + (cu >> 3)) * 256;
        bcol = (cu & 7) * (128 * NW);
    } else {
        const int swz = (bid & 7) * ((int)gridDim.x >> 3) + (bid >> 3);
        brow = (swz & 31) * 256;
        bcol = (swz >> 5) * (128 * NW);
    }
    const int colsw = ((l & 7) ^ (l >> 3)) << 4;

    f32x4 acc[8][2 * NW] = {};
    bf16x8 areg[4][2];
    bf16x8 breg[2][NW][2];

    auto sA = [&](int t, int mh) {
#pragma unroll
        for (int i = 0; i < 2; ++i) {
            int s = (w * 2 + i) * 8 + (l >> 3);
            int r = ((s >> 6) << 7) + mh * 64 + (s & 63);
            const char* src = (const char*)Ap + (((size_t)(brow + r) * K + t * 64) << 1) + colsw;
            __builtin_amdgcn_global_load_lds(
                (const __attribute__((address_space(1))) void*)src,
                (__attribute__((address_space(3))) void*)&lds[(t & 1) * 32768 + mh * 16384 +
                                                              (w * 2 + i) * 1024],
                16, 0, 0);
        }
    };
    auto sB = [&](int t, int nh) {
#pragma unroll
        for (int i = 0; i < NW; ++i) {
            constexpr int SH = (NW == 2) ? 5 : 4;
            int s = (w * NW + i) * 8 + (l >> 3);
            int r = ((s >> SH) << (SH + 1)) + nh * (16 * NW) + (s & (16 * NW - 1));
            const char* src = (const char*)Bp + (((size_t)(bcol + r) * K + t * 64) << 1) + colsw;
            __builtin_amdgcn_global_load_lds(
                (const __attribute__((address_space(1))) void*)src,
                (__attribute__((address_space(3))) void*)&lds[65536 + (t & 1) * (NW * 16384) +
                                                              nh * (NW * 8192) + (w * NW + i) * 1024],
                16, 0, 0);
        }
    };
    auto load_a = [&](int db, int mh) {
#pragma unroll
        for (int m = 0; m < 4; ++m)
#pragma unroll
            for (int ks = 0; ks < 2; ++ks) {
                int s = wm * 64 + m * 16 + (l & 15);
                areg[m][ks] = *(const bf16x8*)(lds + db * 32768 + mh * 16384 + s * 128 +
                                               ((ks * 64 + ((l >> 4) << 4)) ^ ((l & 7) << 4)));
            }
    };
    auto load_b = [&](int db, int nh) {
#pragma unroll
        for (int n = 0; n < NW; ++n)
#pragma unroll
            for (int ks = 0; ks < 2; ++ks) {
                int s = wn * (16 * NW) + n * 16 + (l & 15);
                breg[nh][n][ks] = *(const bf16x8*)(lds + 65536 + db * (NW * 16384) +
                                                   nh * (NW * 8192) + s * 128 +
                                                   ((ks * 64 + ((l >> 4) << 4)) ^ ((l & 7) << 4)));
            }
    };
    auto mma = [&](int mh, int nh) {
#pragma unroll
        for (int m = 0; m < 4; ++m)
#pragma unroll
            for (int n = 0; n < NW; ++n)
#pragma unroll
                for (int ks = 0; ks < 2; ++ks)
                    acc[mh * 4 + m][nh * NW + n] = __builtin_amdgcn_mfma_f32_16x16x32_bf16(
                        areg[m][ks], breg[nh][n][ks], acc[mh * 4 + m][nh * NW + n], 0, 0, 0);
    };

    sA(0, 0); sB(0, 0); sB(0, 1); sA(0, 1);
    vmw<3>();
    barrier_();

    for (int t = 0; t < nt; ++t) {
        const int db = t & 1;
        const bool more = (t + 1 < nt);
        load_a(db, 0); load_b(db, 0);
        if (more) sA(t + 1, 0);
        barrier_(); lgk0_();
        __builtin_amdgcn_s_setprio(1); mma(0, 0); __builtin_amdgcn_s_setprio(0);
        __builtin_amdgcn_sched_barrier(0);
        if (more) vmw<4>(); else vmw<2>();
        barrier_();
        load_b(db, 1);
        if (more) sB(t + 1, 0);
        barrier_(); lgk0_();
        __builtin_amdgcn_s_setprio(1); mma(0, 1); __builtin_amdgcn_s_setprio(0);
        __builtin_amdgcn_sched_barrier(0);
        if (more) vmw<3>(); else vmw<0>();
        barrier_();
        load_a(db, 1);
        if (more) sB(t + 1, 1);
        barrier_(); lgk0_();
        __builtin_amdgcn_s_setprio(1); mma(1, 1); __builtin_amdgcn_s_setprio(0);
        barrier_();
        if (more) sA(t + 1, 1);
        barrier_();
        __builtin_amdgcn_s_setprio(1); mma(1, 0); __builtin_amdgcn_s_setprio(0);
        __builtin_amdgcn_sched_barrier(0);
        if (more) vmw<3>();
        barrier_();
    }

    char* wsl = lds + w * 16384;
    constexpr int E = ACT ? 2 : 4;
    constexpr int BPR = NW * 32 * E;
    constexpr int LPR = BPR / 16;
    constexpr int RPI = 64 / LPR;
#pragma unroll
    for (int m = 0; m < 8; ++m)
#pragma unroll
        for (int n = 0; n < 2 * NW; ++n)
#pragma unroll
            for (int r = 0; r < 4; ++r) {
                int row = m * 16 + ((l >> 4) << 2) + r;
                int colb = (n * 16 + (l & 15)) * E;
                float v = acc[m][n][r];
                if (ACT) {
                    *(ushort*)(wsl + row * 128 + (colb ^ ((row & 7) << 4))) = f2bf(yoso_act(v));
                } else {
                    *(float*)(wsl + row * 128 + (colb ^ ((row & 7) << 4))) = v;
                }
            }
    asm volatile("s_waitcnt lgkmcnt(0)" ::: "memory");
#pragma unroll
    for (int it = 0; it < 2 * LPR; ++it) {
        int row = it * RPI + l / LPR;
        int cb = (l % LPR) * 16;
        uint4 d = *(const uint4*)(wsl + row * 128 + (cb ^ ((row & 7) << 4)));
        int grow = brow + wm * 128 + row;
        size_t off = ((size_t)grow * N + (bcol + wn * (NW * 32))) * E + cb;
        *(uint4*)((char*)Cv + off) = d;
    }
}

// ---------------- Merged prep: LN+qnorm -> fp8 | knorm -> fp8 | q_weight transpose -> bf16 ----------------
__global__ __launch_bounds__(256) void prep_kernel(
    const float* __restrict__ hs, const float* __restrict__ lnw,
    const float* __restrict__ lnb, const float* __restrict__ kw,
    const float* __restrict__ qw, unsigned char* __restrict__ Qf,
    unsigned char* __restrict__ Kf, ushort* __restrict__ VT) {
    __shared__ float smem[64][65];
    const int b = blockIdx.x, t = threadIdx.x;
    const int lane = t & 63, wid = t >> 6;
    if (b < NR) {
        const float4 v = reinterpret_cast<const float4*>(hs + (size_t)b * HD)[t];
        float s  = v.x + v.y + v.z + v.w;
        float ss = v.x*v.x + v.y*v.y + v.z*v.z + v.w*v.w;
        s = wave_sum(s); ss = wave_sum(ss);
        if (lane == 0) { smem[0][wid] = s; smem[1][wid] = ss; }
        __syncthreads();
        float st  = smem[0][0] + smem[0][1] + smem[0][2] + smem[0][3];
        float sst = smem[1][0] + smem[1][1] + smem[1][2] + smem[1][3];
        float mu   = st * (1.0f / HD);
        float var  = sst * (1.0f / HD) - mu * mu;
        float rstd = rsqrtf(var + 1e-12f);
        const float4 wv = reinterpret_cast<const float4*>(lnw)[t];
        const float4 bv = reinterpret_cast<const float4*>(lnb)[t];
        float y0 = (v.x - mu) * rstd * wv.x + bv.x;
        float y1 = (v.y - mu) * rstd * wv.y + bv.y;
        float y2 = (v.z - mu) * rstd * wv.z + bv.z;
        float y3 = (v.w - mu) * rstd * wv.w + bv.w;
        float n2 = wave_sum(y0*y0 + y1*y1 + y2*y2 + y3*y3);
        if (lane == 0) smem[2][wid] = n2;
        __syncthreads();
        float nt2 = smem[2][0] + smem[2][1] + smem[2][2] + smem[2][3];
        float sc = 16.0f / fmaxf(sqrtf(nt2), 1e-12f);   // x16 prescale for fp8
        int r = __builtin_amdgcn_cvt_pk_fp8_f32(y0 * sc, y1 * sc, 0, false);
        r = __builtin_amdgcn_cvt_pk_fp8_f32(y2 * sc, y3 * sc, r, true);
        reinterpret_cast<int*>(Qf + (size_t)b * HD)[t] = r;
    } else if (b < NR + ID) {
        const int row = b - NR;
        const float4 v = reinterpret_cast<const float4*>(kw + (size_t)row * HD)[t];
        float n2 = wave_sum(v.x*v.x + v.y*v.y + v.z*v.z + v.w*v.w);
        if (lane == 0) smem[0][wid] = n2;
        __syncthreads();
        float nt2 = smem[0][0] + smem[0][1] + smem[0][2] + smem[0][3];
        float sc = 16.0f / fmaxf(sqrtf(nt2), 1e-12f);   // x16 prescale for fp8
        int r = __builtin_amdgcn_cvt_pk_fp8_f32(v.x * sc, v.y * sc, 0, false);
        r = __builtin_amdgcn_cvt_pk_fp8_f32(v.z * sc, v.w * sc, r, true);
        reinterpret_cast<int*>(Kf + (size_t)row * HD)[t] = r;
    } else {
        const int b2 = b - NR - ID;
        const int bi = (b2 & 63) * 64, bh = (b2 >> 6) * 64;
        const int r0 = t >> 4, c0 = (t & 15) << 2;
#pragma unroll
        for (int rr = 0; rr < 64; rr += 16) {
            float4 val = *reinterpret_cast<const float4*>(
                &qw[(size_t)(bi + rr + r0) * HD + bh + c0]);
            smem[rr + r0][c0 + 0] = val.x; smem[rr + r0][c0 + 1] = val.y;
            smem[rr + r0][c0 + 2] = val.z; smem[rr + r0][c0 + 3] = val.w;
        }
        __syncthreads();
#pragma unroll
        for (int rr = 0; rr < 64; rr += 16) {
            ushort4 o;
            o.x = f2bf(smem[c0 + 0][rr + r0]);
            o.y = f2bf(smem[c0 + 1][rr + r0]);
            o.z = f2bf(smem[c0 + 2][rr + r0]);
            o.w = f2bf(smem[c0 + 3][rr + r0]);
            *reinterpret_cast<ushort4*>(&VT[(size_t)(bh + rr + r0) * ID + bi + c0]) = o;
        }
    }
}

// ---------------- in-place row l2-normalize + bias ----------------
__global__ __launch_bounds__(256) void outnorm_kernel(
    float* __restrict__ X, const float* __restrict__ bias) {
    __shared__ float red2[4];
    const int row = blockIdx.x, t = threadIdx.x;
    const int lane = t & 63, wid = t >> 6;
    float4 v = reinterpret_cast<float4*>(X + (size_t)row * HD)[t];
    float n2 = wave_sum(v.x*v.x + v.y*v.y + v.z*v.z + v.w*v.w);
    if (lane == 0) red2[wid] = n2;
    __syncthreads();
    float nt = red2[0] + red2[1] + red2[2] + red2[3];
    float sc = 1.0f / fmaxf(sqrtf(nt), 1e-12f);
    const float4 bv = reinterpret_cast<const float4*>(bias)[t];
    float4 o;
    o.x = v.x * sc + bv.x; o.y = v.y * sc + bv.y;
    o.z = v.z * sc + bv.z; o.w = v.w * sc + bv.w;
    reinterpret_cast<float4*>(X + (size_t)row * HD)[t] = o;
}

extern "C" void kernel_launch(void* const* d_in, const int* in_sizes, int n_in,
                              void* d_out, int out_size, void* d_ws, size_t ws_size,
                              hipStream_t stream) {
    const float* hs   = (const float*)d_in[0];  // hidden_states [4,2048,1024]
    const float* lnw  = (const float*)d_in[1];  // ln_weight [1024]
    const float* lnb  = (const float*)d_in[2];  // ln_bias [1024]
    const float* kw   = (const float*)d_in[3];  // k_weight [4096,1024]
    const float* qw   = (const float*)d_in[4];  // q_weight [4096,1024]
    const float* bias = (const float*)d_in[5];  // bias [1024]
    float* out = (float*)d_out;

    char* ws = (char*)d_ws;
    unsigned char* Qf = (unsigned char*)(ws);                       //  8 MiB fp8
    unsigned char* Kf = (unsigned char*)(ws + (size_t)8388608);     //  4 MiB fp8
    ushort* VT   = (ushort*)(ws + (size_t)12582912);                //  8 MiB bf16
    ushort* Bmat = (ushort*)(ws + (size_t)20971520);                // 64 MiB bf16

    // merged prep: 8192 LN rows (fp8) + 4096 K rows (fp8) + 1024 transpose tiles (bf16)
    prep_kernel<<<NR + ID + 1024, 256, 0, stream>>>(hs, lnw, lnb, kw, qw, Qf, Kf, VT);
    // GEMM1: MX-fp8 [8192,1024] x [4096,1024]^T -> act -> Bmat bf16 [8192,4096]
    gemm1f_kernel<<<(NR / 128) * (ID / 128), 256, 0, stream>>>(
        Qf, Kf, Bmat, ID, HD);
    // GEMM2: [8192,4096] x [1024,4096]^T -> out f32 [8192,1024]
    //        banded XCD map (grid 256 = 8 xcd * 32 cu)
    gemm8p_kernel<1, 0, 1><<<(NR / 256) * (HD / 128), 512, 0, stream>>>(
        Bmat, VT, (void*)out, HD, ID, ID / 64);
    outnorm_kernel<<<NR, 256, 0, stream>>>(out, bias);
}